// Round 1
// baseline (1346.285 us; speedup 1.0000x reference)
//
#include <hip/hip_runtime.h>
#include <hip/hip_bf16.h>

typedef __bf16 bf16_t;
typedef __bf16 bf16x8 __attribute__((ext_vector_type(8)));
typedef __bf16 bf16x4 __attribute__((ext_vector_type(4)));
typedef float f32x4 __attribute__((ext_vector_type(4)));
typedef int vint4 __attribute__((ext_vector_type(4)));

constexpr int B_ = 2, T_ = 4096, E_ = 1024, H_ = 16;
constexpr int M_ = B_ * T_;   // 8192 token rows
constexpr int NKV = 256;      // sparse length s = w/r for every scale

// ---------------- f32 -> bf16 elementwise ----------------
__global__ __launch_bounds__(256) void cvt_f32_bf16(const float* __restrict__ in,
                                                    bf16_t* __restrict__ out) {
  int i = (blockIdx.x * 256 + threadIdx.x) * 4;
  const float4 v = *(const float4*)(in + i);
  bf16x4 o;
  o[0] = (bf16_t)v.x; o[1] = (bf16_t)v.y; o[2] = (bf16_t)v.z; o[3] = (bf16_t)v.w;
  *(bf16x4*)(out + i) = o;
}

// ---------------- weights: f32 [K][N] -> bf16 [N][K] (transposed) ----------------
__global__ __launch_bounds__(256) void cvt_transpose_w(
    const float* __restrict__ w0, const float* __restrict__ w1,
    const float* __restrict__ w2, const float* __restrict__ w3,
    bf16_t* __restrict__ o0, bf16_t* __restrict__ o1,
    bf16_t* __restrict__ o2, bf16_t* __restrict__ o3) {
  __shared__ float tile[32][33];
  const float* src; bf16_t* dst;
  switch (blockIdx.z) {
    case 0: src = w0; dst = o0; break;
    case 1: src = w1; dst = o1; break;
    case 2: src = w2; dst = o2; break;
    default: src = w3; dst = o3; break;
  }
  const int n0 = blockIdx.x * 32, k0 = blockIdx.y * 32;
  const int tx = threadIdx.x & 31, ty = threadIdx.x >> 5;  // 32 x 8
#pragma unroll
  for (int i = 0; i < 32; i += 8)
    tile[ty + i][tx] = src[(size_t)(k0 + ty + i) * E_ + n0 + tx];
  __syncthreads();
#pragma unroll
  for (int i = 0; i < 32; i += 8)
    dst[(size_t)(n0 + ty + i) * E_ + k0 + tx] = (bf16_t)tile[tx][ty + i];
}

// ---------------- bf16 MFMA GEMM: C[m][n] = (sum_k A[m][k]*BT[n][k] + bias[n]) * scale ----
#define BM 128
#define BN 128
#define BKk 64

template <bool OUT_BF16>
__global__ __launch_bounds__(256, 2) void gemm_bt(
    const bf16_t* __restrict__ A, const bf16_t* __restrict__ BT,
    const float* __restrict__ bias, float scale, void* __restrict__ Cout,
    int Ndim, int Kdim) {
  __shared__ alignas(16) bf16_t As[BM][BKk + 8];
  __shared__ alignas(16) bf16_t Bs[BN][BKk + 8];
  const int tid = threadIdx.x;
  const int lane = tid & 63;
  const int wave = tid >> 6;
  const int wm = wave >> 1, wn = wave & 1;
  const int bm = blockIdx.x, bn = blockIdx.y;

  f32x4 acc[4][4] = {};

  const int srow = tid >> 3;        // 0..31
  const int scol = (tid & 7) * 8;   // 0..56
  const bf16_t* Ag = A + (size_t)(bm * BM + srow) * Kdim + scol;
  const bf16_t* Bg = BT + (size_t)(bn * BN + srow) * Kdim + scol;

  for (int k0 = 0; k0 < Kdim; k0 += BKk) {
    __syncthreads();
#pragma unroll
    for (int p = 0; p < 4; ++p) {
      *(vint4*)&As[srow + p * 32][scol] = *(const vint4*)(Ag + (size_t)(p * 32) * Kdim + k0);
      *(vint4*)&Bs[srow + p * 32][scol] = *(const vint4*)(Bg + (size_t)(p * 32) * Kdim + k0);
    }
    __syncthreads();
#pragma unroll
    for (int kk = 0; kk < 2; ++kk) {
      bf16x8 af[4], bfr[4];
#pragma unroll
      for (int i = 0; i < 4; ++i) {
        af[i]  = *(const bf16x8*)&As[wm * 64 + i * 16 + (lane & 15)][kk * 32 + (lane >> 4) * 8];
        bfr[i] = *(const bf16x8*)&Bs[wn * 64 + i * 16 + (lane & 15)][kk * 32 + (lane >> 4) * 8];
      }
#pragma unroll
      for (int i = 0; i < 4; ++i)
#pragma unroll
        for (int j = 0; j < 4; ++j)
          acc[i][j] = __builtin_amdgcn_mfma_f32_16x16x32_bf16(af[i], bfr[j], acc[i][j], 0, 0, 0);
    }
  }

#pragma unroll
  for (int i = 0; i < 4; ++i) {
    const int row = bm * BM + wm * 64 + i * 16 + (lane >> 4) * 4;
#pragma unroll
    for (int j = 0; j < 4; ++j) {
      const int col = bn * BN + wn * 64 + j * 16 + (lane & 15);
      const float bv = bias[col];
#pragma unroll
      for (int rg = 0; rg < 4; ++rg) {
        const float v = (acc[i][j][rg] + bv) * scale;
        if (OUT_BF16)
          ((bf16_t*)Cout)[(size_t)(row + rg) * Ndim + col] = (bf16_t)v;
        else
          ((float*)Cout)[(size_t)(row + rg) * Ndim + col] = v;
      }
    }
  }
}

// ---------------- one dilated-attention scale (s=256 queries/keys, d=64) -------------
// block = one (b, segment, head); thread = one sparse query row. Online softmax.
// Merge across scales: running-max logsumexp accumulators (scale 0 covers everything -> FIRST).
template <bool FIRST>
__global__ __launch_bounds__(256, 1) void attn_scale(
    const bf16_t* __restrict__ Q, const bf16_t* __restrict__ K,
    const bf16_t* __restrict__ V, float* __restrict__ Macc,
    float* __restrict__ Sacc, float* __restrict__ Oac, int wseg, int r) {
  __shared__ alignas(16) bf16_t Ks[NKV][64];
  __shared__ alignas(16) bf16_t Vs[NKV][64];
  const int nseg = T_ / wseg;
  int bid = blockIdx.x;
  const int h = bid % H_; bid /= H_;
  const int seg = bid % nseg; bid /= nseg;
  const int b = bid;
  const int hp = H_ / r;
  const int g = h / hp;
  const int l = threadIdx.x;  // sparse query index 0..255

  // stage K/V (8 threads per 64-elem row, 8 passes)
  {
    const int chunk = (threadIdx.x & 7) * 8;
    const int row0 = threadIdx.x >> 3;  // 0..31
#pragma unroll
    for (int p = 0; p < 8; ++p) {
      const int row = row0 + p * 32;
      const int tk = seg * wseg + row * r + g;
      const size_t off = ((size_t)b * T_ + tk) * E_ + h * 64 + chunk;
      *(vint4*)&Ks[row][chunk] = *(const vint4*)(K + off);
      *(vint4*)&Vs[row][chunk] = *(const vint4*)(V + off);
    }
  }

  const int tq = seg * wseg + l * r + g;
  const size_t qoff = ((size_t)b * T_ + tq) * E_ + h * 64;
  float qf[64];
#pragma unroll
  for (int c = 0; c < 8; ++c) {
    bf16x8 qv = *(const bf16x8*)(Q + qoff + c * 8);
#pragma unroll
    for (int e = 0; e < 8; ++e) qf[c * 8 + e] = (float)qv[e];
  }
  __syncthreads();

  float m = -1e30f, Z = 0.0f;
  float oacc[64];
#pragma unroll
  for (int d = 0; d < 64; ++d) oacc[d] = 0.0f;

  const int nkb = (l >> 4) + 1;
  for (int kb = 0; kb < nkb; ++kb) {
    float sc[16];
    float bmax = -1e30f;
#pragma unroll
    for (int j = 0; j < 16; ++j) {
      const int key = kb * 16 + j;
      float dot = 0.0f;
#pragma unroll
      for (int c = 0; c < 8; ++c) {
        bf16x8 kv = *(const bf16x8*)&Ks[key][c * 8];
#pragma unroll
        for (int e = 0; e < 8; ++e) dot += qf[c * 8 + e] * (float)kv[e];
      }
      sc[j] = (key <= l) ? dot : -1e30f;
      bmax = fmaxf(bmax, sc[j]);
    }
    const float newm = fmaxf(m, bmax);
    const float corr = __expf(m - newm);
    Z *= corr;
#pragma unroll
    for (int d = 0; d < 64; ++d) oacc[d] *= corr;
#pragma unroll
    for (int j = 0; j < 16; ++j) {
      const float p = __expf(sc[j] - newm);
      Z += p;
      const int key = kb * 16 + j;
#pragma unroll
      for (int c = 0; c < 8; ++c) {
        bf16x8 vv = *(const bf16x8*)&Vs[key][c * 8];
#pragma unroll
        for (int e = 0; e < 8; ++e) oacc[c * 8 + e] += p * (float)vv[e];
      }
    }
    m = newm;
  }

  const float lse = m + __logf(Z);
  const float invZ = 1.0f / Z;
  const size_t hidx = ((size_t)b * T_ + tq) * H_ + h;
  f32x4* Op = (f32x4*)(Oac + ((size_t)b * T_ + tq) * E_ + h * 64);
  if (FIRST) {
    Macc[hidx] = lse;
    Sacc[hidx] = 1.0f;
#pragma unroll
    for (int c = 0; c < 16; ++c) {
      f32x4 o;
      o[0] = oacc[c * 4 + 0] * invZ;
      o[1] = oacc[c * 4 + 1] * invZ;
      o[2] = oacc[c * 4 + 2] * invZ;
      o[3] = oacc[c * 4 + 3] * invZ;
      Op[c] = o;
    }
  } else {
    const float mold = Macc[hidx];
    const float sold = Sacc[hidx];
    const float newM = fmaxf(mold, lse);
    const float a = __expf(mold - newM);
    const float eb = __expf(lse - newM);
    Macc[hidx] = newM;
    Sacc[hidx] = sold * a + eb;
    const float bw = eb * invZ;
#pragma unroll
    for (int c = 0; c < 16; ++c) {
      f32x4 o = Op[c];
      o[0] = o[0] * a + oacc[c * 4 + 0] * bw;
      o[1] = o[1] * a + oacc[c * 4 + 1] * bw;
      o[2] = o[2] * a + oacc[c * 4 + 2] * bw;
      o[3] = o[3] * a + oacc[c * 4 + 3] * bw;
      Op[c] = o;
    }
  }
}

// ---------------- finalize: y = Oacc / Sacc -> bf16 ----------------
__global__ __launch_bounds__(256) void finalize_y(const float* __restrict__ Oac,
                                                  const float* __restrict__ Sacc,
                                                  bf16_t* __restrict__ y) {
  int i = (blockIdx.x * 256 + threadIdx.x) * 4;
  const float inv = 1.0f / Sacc[i >> 6];
  f32x4 o = *(const f32x4*)(Oac + i);
  bf16x4 rr;
  rr[0] = (bf16_t)(o[0] * inv);
  rr[1] = (bf16_t)(o[1] * inv);
  rr[2] = (bf16_t)(o[2] * inv);
  rr[3] = (bf16_t)(o[3] * inv);
  *(bf16x4*)(y + i) = rr;
}

extern "C" void kernel_launch(void* const* d_in, const int* in_sizes, int n_in,
                              void* d_out, int out_size, void* d_ws, size_t ws_size,
                              hipStream_t stream) {
  (void)in_sizes; (void)n_in; (void)out_size; (void)ws_size;
  const float* x  = (const float*)d_in[0];
  const float* wq = (const float*)d_in[1];
  const float* bq = (const float*)d_in[2];
  const float* wk = (const float*)d_in[3];
  const float* bk = (const float*)d_in[4];
  const float* wv = (const float*)d_in[5];
  const float* bv = (const float*)d_in[6];
  const float* wo = (const float*)d_in[7];
  const float* bo = (const float*)d_in[8];

  char* p = (char*)d_ws;
  auto take = [&](size_t bytes) {
    char* q = p;
    p += (bytes + 255) & ~(size_t)255;
    return (void*)q;
  };
  bf16_t* wq_t = (bf16_t*)take((size_t)E_ * E_ * 2);
  bf16_t* wk_t = (bf16_t*)take((size_t)E_ * E_ * 2);
  bf16_t* wv_t = (bf16_t*)take((size_t)E_ * E_ * 2);
  bf16_t* wo_t = (bf16_t*)take((size_t)E_ * E_ * 2);
  bf16_t* xb   = (bf16_t*)take((size_t)M_ * E_ * 2);
  bf16_t* qb   = (bf16_t*)take((size_t)M_ * E_ * 2);
  bf16_t* kbuf = (bf16_t*)take((size_t)M_ * E_ * 2);
  bf16_t* vbuf = (bf16_t*)take((size_t)M_ * E_ * 2);
  bf16_t* yb   = (bf16_t*)take((size_t)M_ * E_ * 2);
  float* Oac   = (float*)take((size_t)M_ * E_ * 4);
  float* Macc  = (float*)take((size_t)M_ * H_ * 4);
  float* Sacc  = (float*)take((size_t)M_ * H_ * 4);

  cvt_f32_bf16<<<M_ * E_ / 1024, 256, 0, stream>>>(x, xb);
  cvt_transpose_w<<<dim3(32, 32, 4), 256, 0, stream>>>(wq, wk, wv, wo, wq_t, wk_t, wv_t, wo_t);

  dim3 gg(M_ / BM, E_ / BN);
  gemm_bt<true><<<gg, 256, 0, stream>>>(xb, wq_t, bq, 0.125f, qb, E_, E_);
  gemm_bt<true><<<gg, 256, 0, stream>>>(xb, wk_t, bk, 1.0f, kbuf, E_, E_);
  gemm_bt<true><<<gg, 256, 0, stream>>>(xb, wv_t, bv, 1.0f, vbuf, E_, E_);

  attn_scale<true ><<<B_ * (T_ / 256)  * H_, 256, 0, stream>>>(qb, kbuf, vbuf, Macc, Sacc, Oac, 256, 1);
  attn_scale<false><<<B_ * (T_ / 512)  * H_, 256, 0, stream>>>(qb, kbuf, vbuf, Macc, Sacc, Oac, 512, 2);
  attn_scale<false><<<B_ * (T_ / 1024) * H_, 256, 0, stream>>>(qb, kbuf, vbuf, Macc, Sacc, Oac, 1024, 4);
  attn_scale<false><<<B_ * (T_ / 2048) * H_, 256, 0, stream>>>(qb, kbuf, vbuf, Macc, Sacc, Oac, 2048, 8);
  attn_scale<false><<<B_ * (T_ / 4096) * H_, 256, 0, stream>>>(qb, kbuf, vbuf, Macc, Sacc, Oac, 4096, 16);

  finalize_y<<<M_ * E_ / 1024, 256, 0, stream>>>(Oac, Sacc, yb);
  gemm_bt<false><<<gg, 256, 0, stream>>>(yb, wo_t, bo, 1.0f, d_out, E_, E_);
}

// Round 2
// 326.314 us; speedup vs baseline: 4.1257x; 4.1257x over previous
//
#include <hip/hip_runtime.h>
#include <hip/hip_bf16.h>

typedef __bf16 bf16_t;
typedef __bf16 bf16x8 __attribute__((ext_vector_type(8)));
typedef __bf16 bf16x4 __attribute__((ext_vector_type(4)));
typedef float f32x4 __attribute__((ext_vector_type(4)));
typedef int vint4 __attribute__((ext_vector_type(4)));

constexpr int B_ = 2, T_ = 4096, E_ = 1024, H_ = 16;
constexpr int M_ = B_ * T_;   // 8192 token rows

// ---------------- f32 -> bf16 elementwise ----------------
__global__ __launch_bounds__(256) void cvt_f32_bf16(const float* __restrict__ in,
                                                    bf16_t* __restrict__ out) {
  int i = (blockIdx.x * 256 + threadIdx.x) * 4;
  const float4 v = *(const float4*)(in + i);
  bf16x4 o;
  o[0] = (bf16_t)v.x; o[1] = (bf16_t)v.y; o[2] = (bf16_t)v.z; o[3] = (bf16_t)v.w;
  *(bf16x4*)(out + i) = o;
}

// ---------------- weights: f32 [K][N] -> bf16 [N][K] (transposed) ----------------
__global__ __launch_bounds__(256) void cvt_transpose_w(
    const float* __restrict__ w0, const float* __restrict__ w1,
    const float* __restrict__ w2, const float* __restrict__ w3,
    bf16_t* __restrict__ o0, bf16_t* __restrict__ o1,
    bf16_t* __restrict__ o2, bf16_t* __restrict__ o3) {
  __shared__ float tile[32][33];
  const float* src; bf16_t* dst;
  switch (blockIdx.z) {
    case 0: src = w0; dst = o0; break;
    case 1: src = w1; dst = o1; break;
    case 2: src = w2; dst = o2; break;
    default: src = w3; dst = o3; break;
  }
  const int n0 = blockIdx.x * 32, k0 = blockIdx.y * 32;
  const int tx = threadIdx.x & 31, ty = threadIdx.x >> 5;  // 32 x 8
#pragma unroll
  for (int i = 0; i < 32; i += 8)
    tile[ty + i][tx] = src[(size_t)(k0 + ty + i) * E_ + n0 + tx];
  __syncthreads();
#pragma unroll
  for (int i = 0; i < 32; i += 8)
    dst[(size_t)(n0 + ty + i) * E_ + k0 + tx] = (bf16_t)tile[tx][ty + i];
}

// ---------------- bf16 MFMA GEMM: C[m][n] = (sum_k A[m][k]*BT[n][k] + bias[n]) * scale ----
#define BM 128
#define BN 128
#define BKk 64

template <bool OUT_BF16>
__global__ __launch_bounds__(256, 2) void gemm_bt(
    const bf16_t* __restrict__ A, const bf16_t* __restrict__ BT,
    const float* __restrict__ bias, float scale, void* __restrict__ Cout,
    int Ndim, int Kdim) {
  __shared__ alignas(16) bf16_t As[BM][BKk + 8];
  __shared__ alignas(16) bf16_t Bs[BN][BKk + 8];
  const int tid = threadIdx.x;
  const int lane = tid & 63;
  const int wave = tid >> 6;
  const int wm = wave >> 1, wn = wave & 1;
  const int bm = blockIdx.x, bn = blockIdx.y;

  f32x4 acc[4][4] = {};

  const int srow = tid >> 3;        // 0..31
  const int scol = (tid & 7) * 8;   // 0..56
  const bf16_t* Ag = A + (size_t)(bm * BM + srow) * Kdim + scol;
  const bf16_t* Bg = BT + (size_t)(bn * BN + srow) * Kdim + scol;

  for (int k0 = 0; k0 < Kdim; k0 += BKk) {
    __syncthreads();
#pragma unroll
    for (int p = 0; p < 4; ++p) {
      *(vint4*)&As[srow + p * 32][scol] = *(const vint4*)(Ag + (size_t)(p * 32) * Kdim + k0);
      *(vint4*)&Bs[srow + p * 32][scol] = *(const vint4*)(Bg + (size_t)(p * 32) * Kdim + k0);
    }
    __syncthreads();
#pragma unroll
    for (int kk = 0; kk < 2; ++kk) {
      bf16x8 af[4], bfr[4];
#pragma unroll
      for (int i = 0; i < 4; ++i) {
        af[i]  = *(const bf16x8*)&As[wm * 64 + i * 16 + (lane & 15)][kk * 32 + (lane >> 4) * 8];
        bfr[i] = *(const bf16x8*)&Bs[wn * 64 + i * 16 + (lane & 15)][kk * 32 + (lane >> 4) * 8];
      }
#pragma unroll
      for (int i = 0; i < 4; ++i)
#pragma unroll
        for (int j = 0; j < 4; ++j)
          acc[i][j] = __builtin_amdgcn_mfma_f32_16x16x32_bf16(af[i], bfr[j], acc[i][j], 0, 0, 0);
    }
  }

#pragma unroll
  for (int i = 0; i < 4; ++i) {
    const int row = bm * BM + wm * 64 + i * 16 + (lane >> 4) * 4;
#pragma unroll
    for (int j = 0; j < 4; ++j) {
      const int col = bn * BN + wn * 64 + j * 16 + (lane & 15);
      const float bv = bias[col];
#pragma unroll
      for (int rg = 0; rg < 4; ++rg) {
        const float v = (acc[i][j][rg] + bv) * scale;
        if (OUT_BF16)
          ((bf16_t*)Cout)[(size_t)(row + rg) * Ndim + col] = (bf16_t)v;
        else
          ((float*)Cout)[(size_t)(row + rg) * Ndim + col] = v;
      }
    }
  }
}

// ---------------- one dilated-attention scale via MFMA -------------------------------
// block = one (b, segment, head) 256x256 (d=64) causal instance; 8 waves of 64.
// Wave w owns q-row tiles {w, 15-w} (16 rows each). K in LDS [256][72] (padded),
// V transposed in LDS [64][264]. Per 32-key block: 4 S-MFMAs -> in-register online
// softmax (shfl_xor row-reduce) -> P via per-wave LDS scratch -> 4 PV-MFMAs.
// Cross-scale merge through Macc/Sacc/Oac (scale 0 covers everything -> FIRST).
template <bool FIRST>
__global__ __launch_bounds__(512, 4) void attn_scale(
    const bf16_t* __restrict__ Q, const bf16_t* __restrict__ K,
    const bf16_t* __restrict__ V, float* __restrict__ Macc,
    float* __restrict__ Sacc, float* __restrict__ Oac, int wseg, int dil) {
  __shared__ alignas(16) bf16_t Ks[256][72];   // 36864 B
  __shared__ alignas(16) bf16_t Vt[64][264];   // 33792 B
  __shared__ alignas(16) bf16_t Pw[8][16][40]; // 10240 B  (total 80896 B)

  const int nseg = T_ / wseg;
  int bid = blockIdx.x;
  const int h = bid % H_; bid /= H_;
  const int seg = bid % nseg; bid /= nseg;
  const int b = bid;
  const int hp = H_ / dil;
  const int g = h / hp;

  const int t = threadIdx.x;
  const int lane = t & 63;
  const int wv = t >> 6;

  // ---- stage K (row-major, padded) and V (transposed) ----
  {
    const int row = t >> 1, ch = (t & 1) * 32;
    const int tk = seg * wseg + row * dil + g;
    const size_t off = ((size_t)b * T_ + tk) * E_ + h * 64 + ch;
    const bf16_t* Kg = K + off;
    const bf16_t* Vg = V + off;
#pragma unroll
    for (int j = 0; j < 4; ++j)
      *(bf16x8*)&Ks[row][ch + j * 8] = *(const bf16x8*)(Kg + j * 8);
#pragma unroll
    for (int j = 0; j < 4; ++j) {
      bf16x8 va = *(const bf16x8*)(Vg + j * 8);
#pragma unroll
      for (int e = 0; e < 8; ++e) Vt[ch + j * 8 + e][row] = va[e];
    }
  }
  __syncthreads();

  const int lc = lane & 15;       // MFMA col lane
  const int lg = lane >> 4;       // MFMA 16-lane group 0..3

#pragma unroll
  for (int sel = 0; sel < 2; ++sel) {
    const int qf = sel ? (15 - wv) : wv;   // 16-row q tile index

    // Q fragments for this tile (A-frag: row=lc, k=(lg)*8.. per 32-k block)
    const int qrow = qf * 16 + lc;
    const int tq = seg * wseg + qrow * dil + g;
    const bf16_t* Qg = Q + ((size_t)b * T_ + tq) * E_ + h * 64 + lg * 8;
    bf16x8 qfrag[2];
    qfrag[0] = *(const bf16x8*)(Qg);
    qfrag[1] = *(const bf16x8*)(Qg + 32);

    float m[4], Z[4];
    f32x4 Oa[4] = {};
#pragma unroll
    for (int rg = 0; rg < 4; ++rg) { m[rg] = -INFINITY; Z[rg] = 0.0f; }

    const int nkb = qf / 2 + 1;  // 32-key blocks needed (causal)
    const int diag = qf / 2;
    for (int kb = 0; kb < nkb; ++kb) {
      // ---- S = Q K^T tile (16q x 32k) ----
      f32x4 sacc[2] = {};
#pragma unroll
      for (int kt = 0; kt < 2; ++kt)
#pragma unroll
        for (int kd = 0; kd < 2; ++kd) {
          bf16x8 kf = *(const bf16x8*)&Ks[kb * 32 + kt * 16 + lc][kd * 32 + lg * 8];
          sacc[kt] = __builtin_amdgcn_mfma_f32_16x16x32_bf16(qfrag[kd], kf, sacc[kt], 0, 0, 0);
        }
      // causal mask on diagonal block: acc layout col=lc(key), row=lg*4+rg(q)
      if (kb == diag) {
#pragma unroll
        for (int kt = 0; kt < 2; ++kt) {
          const int key = kb * 32 + kt * 16 + lc;
#pragma unroll
          for (int rg = 0; rg < 4; ++rg) {
            const int qq = qf * 16 + lg * 4 + rg;
            if (key > qq) sacc[kt][rg] = -1e30f;
          }
        }
      }
      // ---- online softmax per q row ----
      float crr[4];
#pragma unroll
      for (int rg = 0; rg < 4; ++rg) {
        float bm = fmaxf(sacc[0][rg], sacc[1][rg]);
        bm = fmaxf(bm, __shfl_xor(bm, 1));
        bm = fmaxf(bm, __shfl_xor(bm, 2));
        bm = fmaxf(bm, __shfl_xor(bm, 4));
        bm = fmaxf(bm, __shfl_xor(bm, 8));
        const float nm = fmaxf(m[rg], bm);
        crr[rg] = __expf(m[rg] - nm);
        m[rg] = nm;
        const float p0 = __expf(sacc[0][rg] - nm);
        const float p1 = __expf(sacc[1][rg] - nm);
        float ps = p0 + p1;
        ps += __shfl_xor(ps, 1);
        ps += __shfl_xor(ps, 2);
        ps += __shfl_xor(ps, 4);
        ps += __shfl_xor(ps, 8);
        Z[rg] = Z[rg] * crr[rg] + ps;
        Pw[wv][lg * 4 + rg][lc] = (bf16_t)p0;
        Pw[wv][lg * 4 + rg][16 + lc] = (bf16_t)p1;
      }
#pragma unroll
      for (int dt = 0; dt < 4; ++dt)
#pragma unroll
        for (int rg = 0; rg < 4; ++rg) Oa[dt][rg] *= crr[rg];
      // ---- PV: O += P V  (A-frag = P rows, B-frag = Vt rows) ----
      bf16x8 pa = *(const bf16x8*)&Pw[wv][lc][lg * 8];
#pragma unroll
      for (int dt = 0; dt < 4; ++dt) {
        bf16x8 vf = *(const bf16x8*)&Vt[dt * 16 + lc][kb * 32 + lg * 8];
        Oa[dt] = __builtin_amdgcn_mfma_f32_16x16x32_bf16(pa, vf, Oa[dt], 0, 0, 0);
      }
    }

    // ---- epilogue: merge into cross-scale accumulators ----
#pragma unroll
    for (int rg = 0; rg < 4; ++rg) {
      const int qq = qf * 16 + lg * 4 + rg;
      const int tqo = seg * wseg + qq * dil + g;
      const size_t rowbase = ((size_t)b * T_ + tqo) * E_ + h * 64;
      const size_t hidx = ((size_t)b * T_ + tqo) * H_ + h;
      const float lse = m[rg] + __logf(Z[rg]);
      const float iZ = 1.0f / Z[rg];
      if (FIRST) {
#pragma unroll
        for (int dt = 0; dt < 4; ++dt)
          Oac[rowbase + dt * 16 + lc] = Oa[dt][rg] * iZ;
        if (lc == 0) { Macc[hidx] = lse; Sacc[hidx] = 1.0f; }
      } else {
        const float mold = Macc[hidx];
        const float sold = Sacc[hidx];
        const float nM = fmaxf(mold, lse);
        const float a = __expf(mold - nM);
        const float eb = __expf(lse - nM);
        const float bw = eb * iZ;
#pragma unroll
        for (int dt = 0; dt < 4; ++dt) {
          const size_t idx = rowbase + dt * 16 + lc;
          Oac[idx] = Oac[idx] * a + Oa[dt][rg] * bw;
        }
        if (lc == 0) { Macc[hidx] = nM; Sacc[hidx] = sold * a + eb; }
      }
    }
  }
}

// ---------------- finalize: y = Oacc / Sacc -> bf16 ----------------
__global__ __launch_bounds__(256) void finalize_y(const float* __restrict__ Oac,
                                                  const float* __restrict__ Sacc,
                                                  bf16_t* __restrict__ y) {
  int i = (blockIdx.x * 256 + threadIdx.x) * 4;
  const float inv = 1.0f / Sacc[i >> 6];
  f32x4 o = *(const f32x4*)(Oac + i);
  bf16x4 rr;
  rr[0] = (bf16_t)(o[0] * inv);
  rr[1] = (bf16_t)(o[1] * inv);
  rr[2] = (bf16_t)(o[2] * inv);
  rr[3] = (bf16_t)(o[3] * inv);
  *(bf16x4*)(y + i) = rr;
}

extern "C" void kernel_launch(void* const* d_in, const int* in_sizes, int n_in,
                              void* d_out, int out_size, void* d_ws, size_t ws_size,
                              hipStream_t stream) {
  (void)in_sizes; (void)n_in; (void)out_size; (void)ws_size;
  const float* x  = (const float*)d_in[0];
  const float* wq = (const float*)d_in[1];
  const float* bq = (const float*)d_in[2];
  const float* wk = (const float*)d_in[3];
  const float* bk = (const float*)d_in[4];
  const float* wv = (const float*)d_in[5];
  const float* bv = (const float*)d_in[6];
  const float* wo = (const float*)d_in[7];
  const float* bo = (const float*)d_in[8];

  char* p = (char*)d_ws;
  auto take = [&](size_t bytes) {
    char* q = p;
    p += (bytes + 255) & ~(size_t)255;
    return (void*)q;
  };
  bf16_t* wq_t = (bf16_t*)take((size_t)E_ * E_ * 2);
  bf16_t* wk_t = (bf16_t*)take((size_t)E_ * E_ * 2);
  bf16_t* wv_t = (bf16_t*)take((size_t)E_ * E_ * 2);
  bf16_t* wo_t = (bf16_t*)take((size_t)E_ * E_ * 2);
  bf16_t* xb   = (bf16_t*)take((size_t)M_ * E_ * 2);
  bf16_t* qb   = (bf16_t*)take((size_t)M_ * E_ * 2);
  bf16_t* kbuf = (bf16_t*)take((size_t)M_ * E_ * 2);
  bf16_t* vbuf = (bf16_t*)take((size_t)M_ * E_ * 2);
  bf16_t* yb   = (bf16_t*)take((size_t)M_ * E_ * 2);
  float* Oac   = (float*)take((size_t)M_ * E_ * 4);
  float* Macc  = (float*)take((size_t)M_ * H_ * 4);
  float* Sacc  = (float*)take((size_t)M_ * H_ * 4);

  cvt_f32_bf16<<<M_ * E_ / 1024, 256, 0, stream>>>(x, xb);
  cvt_transpose_w<<<dim3(32, 32, 4), 256, 0, stream>>>(wq, wk, wv, wo, wq_t, wk_t, wv_t, wo_t);

  dim3 gg(M_ / BM, E_ / BN);
  gemm_bt<true><<<gg, 256, 0, stream>>>(xb, wq_t, bq, 0.125f, qb, E_, E_);
  gemm_bt<true><<<gg, 256, 0, stream>>>(xb, wk_t, bk, 1.0f, kbuf, E_, E_);
  gemm_bt<true><<<gg, 256, 0, stream>>>(xb, wv_t, bv, 1.0f, vbuf, E_, E_);

  attn_scale<true ><<<B_ * (T_ / 256)  * H_, 512, 0, stream>>>(qb, kbuf, vbuf, Macc, Sacc, Oac, 256, 1);
  attn_scale<false><<<B_ * (T_ / 512)  * H_, 512, 0, stream>>>(qb, kbuf, vbuf, Macc, Sacc, Oac, 512, 2);
  attn_scale<false><<<B_ * (T_ / 1024) * H_, 512, 0, stream>>>(qb, kbuf, vbuf, Macc, Sacc, Oac, 1024, 4);
  attn_scale<false><<<B_ * (T_ / 2048) * H_, 512, 0, stream>>>(qb, kbuf, vbuf, Macc, Sacc, Oac, 2048, 8);
  attn_scale<false><<<B_ * (T_ / 4096) * H_, 512, 0, stream>>>(qb, kbuf, vbuf, Macc, Sacc, Oac, 4096, 16);

  finalize_y<<<M_ * E_ / 1024, 256, 0, stream>>>(Oac, Sacc, yb);
  gemm_bt<false><<<gg, 256, 0, stream>>>(yb, wo_t, bo, 1.0f, d_out, E_, E_);
}

// Round 3
// 221.807 us; speedup vs baseline: 6.0696x; 1.4712x over previous
//
#include <hip/hip_runtime.h>
#include <hip/hip_bf16.h>

typedef __bf16 bf16_t;
typedef __bf16 bf16x8 __attribute__((ext_vector_type(8)));
typedef __bf16 bf16x4 __attribute__((ext_vector_type(4)));
typedef float f32x4 __attribute__((ext_vector_type(4)));
typedef int vint4 __attribute__((ext_vector_type(4)));

constexpr int B_ = 2, T_ = 4096, E_ = 1024, H_ = 16;
constexpr int M_ = B_ * T_;   // 8192 token rows

// ---------------- f32 -> bf16 elementwise ----------------
__global__ __launch_bounds__(256) void cvt_f32_bf16(const float* __restrict__ in,
                                                    bf16_t* __restrict__ out) {
  int i = (blockIdx.x * 256 + threadIdx.x) * 4;
  const float4 v = *(const float4*)(in + i);
  bf16x4 o;
  o[0] = (bf16_t)v.x; o[1] = (bf16_t)v.y; o[2] = (bf16_t)v.z; o[3] = (bf16_t)v.w;
  *(bf16x4*)(out + i) = o;
}

// ---------------- weights: f32 [K][N] -> bf16 [N][K] (transposed) ----------------
__global__ __launch_bounds__(256) void cvt_transpose_w(
    const float* __restrict__ w0, const float* __restrict__ w1,
    const float* __restrict__ w2, const float* __restrict__ w3,
    bf16_t* __restrict__ o0, bf16_t* __restrict__ o1,
    bf16_t* __restrict__ o2, bf16_t* __restrict__ o3) {
  __shared__ float tile[32][33];
  const float* src; bf16_t* dst;
  switch (blockIdx.z) {
    case 0: src = w0; dst = o0; break;
    case 1: src = w1; dst = o1; break;
    case 2: src = w2; dst = o2; break;
    default: src = w3; dst = o3; break;
  }
  const int n0 = blockIdx.x * 32, k0 = blockIdx.y * 32;
  const int tx = threadIdx.x & 31, ty = threadIdx.x >> 5;  // 32 x 8
#pragma unroll
  for (int i = 0; i < 32; i += 8)
    tile[ty + i][tx] = src[(size_t)(k0 + ty + i) * E_ + n0 + tx];
  __syncthreads();
#pragma unroll
  for (int i = 0; i < 32; i += 8)
    dst[(size_t)(n0 + ty + i) * E_ + k0 + tx] = (bf16_t)tile[tx][ty + i];
}

// ---------------- bf16 MFMA GEMM (m97 structure: linear LDS + global_load_lds w16) ----
// C[m][n] = (sum_k A[m][k]*BT[n][k] + bias[n]) * scale
// QKV=true: BT is 3 contiguous [E][E] weight mats, out = 3 contiguous [M][E] bf16 bufs.
#define BM 128
#define BN 128
#define BKg 64

template <bool OUT_BF16, bool QKV>
__global__ __launch_bounds__(256, 2) void gemm_bt(
    const bf16_t* __restrict__ A, const bf16_t* __restrict__ BT,
    const float* __restrict__ bias0, const float* __restrict__ bias1,
    const float* __restrict__ bias2, void* __restrict__ Cout, int Kdim) {
  __shared__ bf16_t As[BM * BKg];
  __shared__ bf16_t Bs[BN * BKg];
  const int tid = threadIdx.x;
  const int lane = tid & 63;
  const int wave = tid >> 6;
  const int wm = wave >> 1, wn = wave & 1;
  const int bm = blockIdx.x;
  int bn = blockIdx.y;

  const float* bias = bias0;
  float scale = 1.0f;
  void* outp = Cout;
  if (QKV) {
    const int which = bn >> 3;
    bn &= 7;
    bias = (which == 0) ? bias0 : (which == 1) ? bias1 : bias2;
    scale = (which == 0) ? 0.125f : 1.0f;
    outp = (void*)((bf16_t*)Cout + (size_t)which * M_ * E_);
    BT += (size_t)which * E_ * E_;
  }

  f32x4 acc[4][4] = {};

  const int lrow = tid >> 3;        // 0..31
  const int lcol = (tid & 7) * 8;   // element col 0..56
  const bf16_t* Ag = A + (size_t)(bm * BM + lrow) * Kdim + lcol;
  const bf16_t* Bg = BT + (size_t)(bn * BN + lrow) * Kdim + lcol;
  bf16_t* Asd = &As[lrow * BKg + lcol];
  bf16_t* Bsd = &Bs[lrow * BKg + lcol];

  for (int k0 = 0; k0 < Kdim; k0 += BKg) {
    __syncthreads();
#pragma unroll
    for (int j = 0; j < 4; ++j) {
      __builtin_amdgcn_global_load_lds(
          (const __attribute__((address_space(1))) void*)(Ag + (size_t)(j * 32) * Kdim + k0),
          (__attribute__((address_space(3))) void*)(Asd + j * 32 * BKg), 16, 0, 0);
      __builtin_amdgcn_global_load_lds(
          (const __attribute__((address_space(1))) void*)(Bg + (size_t)(j * 32) * Kdim + k0),
          (__attribute__((address_space(3))) void*)(Bsd + j * 32 * BKg), 16, 0, 0);
    }
    __syncthreads();
#pragma unroll
    for (int kk = 0; kk < 2; ++kk) {
      bf16x8 af[4], bfr[4];
#pragma unroll
      for (int i = 0; i < 4; ++i) {
        af[i]  = *(const bf16x8*)&As[(wm * 64 + i * 16 + (lane & 15)) * BKg + kk * 32 + (lane >> 4) * 8];
        bfr[i] = *(const bf16x8*)&Bs[(wn * 64 + i * 16 + (lane & 15)) * BKg + kk * 32 + (lane >> 4) * 8];
      }
#pragma unroll
      for (int i = 0; i < 4; ++i)
#pragma unroll
        for (int j = 0; j < 4; ++j)
          acc[i][j] = __builtin_amdgcn_mfma_f32_16x16x32_bf16(af[i], bfr[j], acc[i][j], 0, 0, 0);
    }
  }

#pragma unroll
  for (int i = 0; i < 4; ++i) {
    const int row = bm * BM + wm * 64 + i * 16 + (lane >> 4) * 4;
#pragma unroll
    for (int j = 0; j < 4; ++j) {
      const int col = bn * BN + wn * 64 + j * 16 + (lane & 15);
      const float bv = bias[col];
#pragma unroll
      for (int rg = 0; rg < 4; ++rg) {
        const float v = (acc[i][j][rg] + bv) * scale;
        if (OUT_BF16)
          ((bf16_t*)outp)[(size_t)(row + rg) * E_ + col] = (bf16_t)v;
        else
          ((float*)outp)[(size_t)(row + rg) * E_ + col] = v;
      }
    }
  }
}

// ---------------- one dilated-attention scale via MFMA -------------------------------
// block = one (b, segment, head) 256x256 (d=64) causal instance; 8 waves of 64.
// Wave w owns q-row tiles {w, 15-w} (16 rows each). K in LDS [256][72] (padded),
// V transposed in LDS [64][264]. Per 32-key block: 4 S-MFMAs -> in-register online
// softmax (shfl_xor row-reduce) -> P via per-wave LDS scratch -> 4 PV-MFMAs.
// Cross-scale merge through Macc/Sacc/Oac (scale 0 covers everything -> FIRST).
template <bool FIRST>
__global__ __launch_bounds__(512, 4) void attn_scale(
    const bf16_t* __restrict__ Q, const bf16_t* __restrict__ K,
    const bf16_t* __restrict__ V, float* __restrict__ Macc,
    float* __restrict__ Sacc, float* __restrict__ Oac, int wseg, int dil) {
  __shared__ alignas(16) bf16_t Ks[256][72];   // 36864 B
  __shared__ alignas(16) bf16_t Vt[64][264];   // 33792 B
  __shared__ alignas(16) bf16_t Pw[8][16][40]; // 10240 B  (total 80896 B)

  const int nseg = T_ / wseg;
  int bid = blockIdx.x;
  const int h = bid % H_; bid /= H_;
  const int seg = bid % nseg; bid /= nseg;
  const int b = bid;
  const int hp = H_ / dil;
  const int g = h / hp;

  const int t = threadIdx.x;
  const int lane = t & 63;
  const int wv = t >> 6;

  // ---- stage K (row-major, padded) and V (transposed) ----
  {
    const int row = t >> 1, ch = (t & 1) * 32;
    const int tk = seg * wseg + row * dil + g;
    const size_t off = ((size_t)b * T_ + tk) * E_ + h * 64 + ch;
    const bf16_t* Kg = K + off;
    const bf16_t* Vg = V + off;
#pragma unroll
    for (int j = 0; j < 4; ++j)
      *(bf16x8*)&Ks[row][ch + j * 8] = *(const bf16x8*)(Kg + j * 8);
#pragma unroll
    for (int j = 0; j < 4; ++j) {
      bf16x8 va = *(const bf16x8*)(Vg + j * 8);
#pragma unroll
      for (int e = 0; e < 8; ++e) Vt[ch + j * 8 + e][row] = va[e];
    }
  }
  __syncthreads();

  const int lc = lane & 15;       // MFMA col lane
  const int lg = lane >> 4;       // MFMA 16-lane group 0..3

#pragma unroll
  for (int sel = 0; sel < 2; ++sel) {
    const int qf = sel ? (15 - wv) : wv;   // 16-row q tile index

    // Q fragments for this tile (A-frag: row=lc, k=(lg)*8.. per 32-k block)
    const int qrow = qf * 16 + lc;
    const int tq = seg * wseg + qrow * dil + g;
    const bf16_t* Qg = Q + ((size_t)b * T_ + tq) * E_ + h * 64 + lg * 8;
    bf16x8 qfrag[2];
    qfrag[0] = *(const bf16x8*)(Qg);
    qfrag[1] = *(const bf16x8*)(Qg + 32);

    float m[4], Z[4];
    f32x4 Oa[4] = {};
#pragma unroll
    for (int rg = 0; rg < 4; ++rg) { m[rg] = -INFINITY; Z[rg] = 0.0f; }

    const int nkb = qf / 2 + 1;  // 32-key blocks needed (causal)
    const int diag = qf / 2;
    for (int kb = 0; kb < nkb; ++kb) {
      // ---- S = Q K^T tile (16q x 32k) ----
      f32x4 sacc[2] = {};
#pragma unroll
      for (int kt = 0; kt < 2; ++kt)
#pragma unroll
        for (int kd = 0; kd < 2; ++kd) {
          bf16x8 kf = *(const bf16x8*)&Ks[kb * 32 + kt * 16 + lc][kd * 32 + lg * 8];
          sacc[kt] = __builtin_amdgcn_mfma_f32_16x16x32_bf16(qfrag[kd], kf, sacc[kt], 0, 0, 0);
        }
      // causal mask on diagonal block: acc layout col=lc(key), row=lg*4+rg(q)
      if (kb == diag) {
#pragma unroll
        for (int kt = 0; kt < 2; ++kt) {
          const int key = kb * 32 + kt * 16 + lc;
#pragma unroll
          for (int rg = 0; rg < 4; ++rg) {
            const int qq = qf * 16 + lg * 4 + rg;
            if (key > qq) sacc[kt][rg] = -1e30f;
          }
        }
      }
      // ---- online softmax per q row ----
      float crr[4];
#pragma unroll
      for (int rg = 0; rg < 4; ++rg) {
        float bm = fmaxf(sacc[0][rg], sacc[1][rg]);
        bm = fmaxf(bm, __shfl_xor(bm, 1));
        bm = fmaxf(bm, __shfl_xor(bm, 2));
        bm = fmaxf(bm, __shfl_xor(bm, 4));
        bm = fmaxf(bm, __shfl_xor(bm, 8));
        const float nm = fmaxf(m[rg], bm);
        crr[rg] = __expf(m[rg] - nm);
        m[rg] = nm;
        const float p0 = __expf(sacc[0][rg] - nm);
        const float p1 = __expf(sacc[1][rg] - nm);
        float ps = p0 + p1;
        ps += __shfl_xor(ps, 1);
        ps += __shfl_xor(ps, 2);
        ps += __shfl_xor(ps, 4);
        ps += __shfl_xor(ps, 8);
        Z[rg] = Z[rg] * crr[rg] + ps;
        Pw[wv][lg * 4 + rg][lc] = (bf16_t)p0;
        Pw[wv][lg * 4 + rg][16 + lc] = (bf16_t)p1;
      }
#pragma unroll
      for (int dt = 0; dt < 4; ++dt)
#pragma unroll
        for (int rg = 0; rg < 4; ++rg) Oa[dt][rg] *= crr[rg];
      // ---- PV: O += P V  (A-frag = P rows, B-frag = Vt rows) ----
      bf16x8 pa = *(const bf16x8*)&Pw[wv][lc][lg * 8];
#pragma unroll
      for (int dt = 0; dt < 4; ++dt) {
        bf16x8 vf = *(const bf16x8*)&Vt[dt * 16 + lc][kb * 32 + lg * 8];
        Oa[dt] = __builtin_amdgcn_mfma_f32_16x16x32_bf16(pa, vf, Oa[dt], 0, 0, 0);
      }
    }

    // ---- epilogue: merge into cross-scale accumulators ----
#pragma unroll
    for (int rg = 0; rg < 4; ++rg) {
      const int qq = qf * 16 + lg * 4 + rg;
      const int tqo = seg * wseg + qq * dil + g;
      const size_t rowbase = ((size_t)b * T_ + tqo) * E_ + h * 64;
      const size_t hidx = ((size_t)b * T_ + tqo) * H_ + h;
      const float lse = m[rg] + __logf(Z[rg]);
      const float iZ = 1.0f / Z[rg];
      if (FIRST) {
#pragma unroll
        for (int dt = 0; dt < 4; ++dt)
          Oac[rowbase + dt * 16 + lc] = Oa[dt][rg] * iZ;
        if (lc == 0) { Macc[hidx] = lse; Sacc[hidx] = 1.0f; }
      } else {
        const float mold = Macc[hidx];
        const float sold = Sacc[hidx];
        const float nM = fmaxf(mold, lse);
        const float a = __expf(mold - nM);
        const float eb = __expf(lse - nM);
        const float bw = eb * iZ;
#pragma unroll
        for (int dt = 0; dt < 4; ++dt) {
          const size_t idx = rowbase + dt * 16 + lc;
          Oac[idx] = Oac[idx] * a + Oa[dt][rg] * bw;
        }
        if (lc == 0) { Macc[hidx] = nM; Sacc[hidx] = sold * a + eb; }
      }
    }
  }
}

// ---------------- finalize: y = Oacc / Sacc -> bf16 ----------------
__global__ __launch_bounds__(256) void finalize_y(const float* __restrict__ Oac,
                                                  const float* __restrict__ Sacc,
                                                  bf16_t* __restrict__ y) {
  int i = (blockIdx.x * 256 + threadIdx.x) * 4;
  const float inv = 1.0f / Sacc[i >> 6];
  f32x4 o = *(const f32x4*)(Oac + i);
  bf16x4 rr;
  rr[0] = (bf16_t)(o[0] * inv);
  rr[1] = (bf16_t)(o[1] * inv);
  rr[2] = (bf16_t)(o[2] * inv);
  rr[3] = (bf16_t)(o[3] * inv);
  *(bf16x4*)(y + i) = rr;
}

extern "C" void kernel_launch(void* const* d_in, const int* in_sizes, int n_in,
                              void* d_out, int out_size, void* d_ws, size_t ws_size,
                              hipStream_t stream) {
  (void)in_sizes; (void)n_in; (void)out_size; (void)ws_size;
  const float* x  = (const float*)d_in[0];
  const float* wq = (const float*)d_in[1];
  const float* bq = (const float*)d_in[2];
  const float* wk = (const float*)d_in[3];
  const float* bk = (const float*)d_in[4];
  const float* wv = (const float*)d_in[5];
  const float* bv = (const float*)d_in[6];
  const float* wo = (const float*)d_in[7];
  const float* bo = (const float*)d_in[8];

  char* p = (char*)d_ws;
  auto take = [&](size_t bytes) {
    char* q = p;
    p += (bytes + 255) & ~(size_t)255;
    return (void*)q;
  };
  bf16_t* wq_t = (bf16_t*)take((size_t)E_ * E_ * 2);  // wq_t/wk_t/wv_t contiguous
  bf16_t* wk_t = (bf16_t*)take((size_t)E_ * E_ * 2);
  bf16_t* wv_t = (bf16_t*)take((size_t)E_ * E_ * 2);
  bf16_t* wo_t = (bf16_t*)take((size_t)E_ * E_ * 2);
  bf16_t* xb   = (bf16_t*)take((size_t)M_ * E_ * 2);
  bf16_t* qb   = (bf16_t*)take((size_t)M_ * E_ * 2);  // qb/kbuf/vbuf contiguous
  bf16_t* kbuf = (bf16_t*)take((size_t)M_ * E_ * 2);
  bf16_t* vbuf = (bf16_t*)take((size_t)M_ * E_ * 2);
  bf16_t* yb   = (bf16_t*)take((size_t)M_ * E_ * 2);
  float* Oac   = (float*)take((size_t)M_ * E_ * 4);
  float* Macc  = (float*)take((size_t)M_ * H_ * 4);
  float* Sacc  = (float*)take((size_t)M_ * H_ * 4);

  cvt_f32_bf16<<<M_ * E_ / 1024, 256, 0, stream>>>(x, xb);
  cvt_transpose_w<<<dim3(32, 32, 4), 256, 0, stream>>>(wq, wk, wv, wo, wq_t, wk_t, wv_t, wo_t);

  // Fused Q/K/V projection: grid (64, 24), output-buffer select on bn>>3.
  gemm_bt<true, true><<<dim3(M_ / BM, 3 * E_ / BN), 256, 0, stream>>>(
      xb, wq_t, bq, bk, bv, qb, E_);

  attn_scale<true ><<<B_ * (T_ / 256)  * H_, 512, 0, stream>>>(qb, kbuf, vbuf, Macc, Sacc, Oac, 256, 1);
  attn_scale<false><<<B_ * (T_ / 512)  * H_, 512, 0, stream>>>(qb, kbuf, vbuf, Macc, Sacc, Oac, 512, 2);
  attn_scale<false><<<B_ * (T_ / 1024) * H_, 512, 0, stream>>>(qb, kbuf, vbuf, Macc, Sacc, Oac, 1024, 4);
  attn_scale<false><<<B_ * (T_ / 2048) * H_, 512, 0, stream>>>(qb, kbuf, vbuf, Macc, Sacc, Oac, 2048, 8);
  attn_scale<false><<<B_ * (T_ / 4096) * H_, 512, 0, stream>>>(qb, kbuf, vbuf, Macc, Sacc, Oac, 4096, 16);

  finalize_y<<<M_ * E_ / 1024, 256, 0, stream>>>(Oac, Sacc, yb);
  gemm_bt<false, false><<<dim3(M_ / BM, E_ / BN), 256, 0, stream>>>(
      yb, wo_t, bo, bo, bo, d_out, E_);
}

// Round 4
// 206.278 us; speedup vs baseline: 6.5266x; 1.0753x over previous
//
#include <hip/hip_runtime.h>
#include <hip/hip_bf16.h>

typedef __bf16 bf16_t;
typedef __bf16 bf16x8 __attribute__((ext_vector_type(8)));
typedef __bf16 bf16x4 __attribute__((ext_vector_type(4)));
typedef float f32x4 __attribute__((ext_vector_type(4)));
typedef int vint4 __attribute__((ext_vector_type(4)));

constexpr int B_ = 2, T_ = 4096, E_ = 1024, H_ = 16;
constexpr int M_ = B_ * T_;   // 8192 token rows

// ---------------- f32 -> bf16 elementwise ----------------
__global__ __launch_bounds__(256) void cvt_f32_bf16(const float* __restrict__ in,
                                                    bf16_t* __restrict__ out) {
  int i = (blockIdx.x * 256 + threadIdx.x) * 4;
  const float4 v = *(const float4*)(in + i);
  bf16x4 o;
  o[0] = (bf16_t)v.x; o[1] = (bf16_t)v.y; o[2] = (bf16_t)v.z; o[3] = (bf16_t)v.w;
  *(bf16x4*)(out + i) = o;
}

// ---------------- weights: f32 [K][N] -> bf16 [N][K] (transposed) ----------------
__global__ __launch_bounds__(256) void cvt_transpose_w(
    const float* __restrict__ w0, const float* __restrict__ w1,
    const float* __restrict__ w2, const float* __restrict__ w3,
    bf16_t* __restrict__ o0, bf16_t* __restrict__ o1,
    bf16_t* __restrict__ o2, bf16_t* __restrict__ o3) {
  __shared__ float tile[32][33];
  const float* src; bf16_t* dst;
  switch (blockIdx.z) {
    case 0: src = w0; dst = o0; break;
    case 1: src = w1; dst = o1; break;
    case 2: src = w2; dst = o2; break;
    default: src = w3; dst = o3; break;
  }
  const int n0 = blockIdx.x * 32, k0 = blockIdx.y * 32;
  const int tx = threadIdx.x & 31, ty = threadIdx.x >> 5;  // 32 x 8
#pragma unroll
  for (int i = 0; i < 32; i += 8)
    tile[ty + i][tx] = src[(size_t)(k0 + ty + i) * E_ + n0 + tx];
  __syncthreads();
#pragma unroll
  for (int i = 0; i < 32; i += 8)
    dst[(size_t)(n0 + ty + i) * E_ + k0 + tx] = (bf16_t)tile[tx][ty + i];
}

// ---------------- bf16 MFMA GEMM (m97 structure: linear LDS + global_load_lds w16) ----
// C[m][n] = (sum_k A[m][k]*BT[n][k] + bias[n]) * scale
// QKV=true: BT is 3 contiguous [E][E] weight mats, out = 3 contiguous [M][E] bf16 bufs.
#define BM 128
#define BN 128
#define BKg 64

template <bool OUT_BF16, bool QKV>
__global__ __launch_bounds__(256, 2) void gemm_bt(
    const bf16_t* __restrict__ A, const bf16_t* __restrict__ BT,
    const float* __restrict__ bias0, const float* __restrict__ bias1,
    const float* __restrict__ bias2, void* __restrict__ Cout, int Kdim) {
  __shared__ bf16_t As[BM * BKg];
  __shared__ bf16_t Bs[BN * BKg];
  const int tid = threadIdx.x;
  const int lane = tid & 63;
  const int wave = tid >> 6;
  const int wm = wave >> 1, wn = wave & 1;
  const int bm = blockIdx.x;
  int bn = blockIdx.y;

  const float* bias = bias0;
  float scale = 1.0f;
  void* outp = Cout;
  if (QKV) {
    const int which = bn >> 3;
    bn &= 7;
    bias = (which == 0) ? bias0 : (which == 1) ? bias1 : bias2;
    scale = (which == 0) ? 0.125f : 1.0f;
    outp = (void*)((bf16_t*)Cout + (size_t)which * M_ * E_);
    BT += (size_t)which * E_ * E_;
  }

  f32x4 acc[4][4] = {};

  const int lrow = tid >> 3;        // 0..31
  const int lcol = (tid & 7) * 8;   // element col 0..56
  const bf16_t* Ag = A + (size_t)(bm * BM + lrow) * Kdim + lcol;
  const bf16_t* Bg = BT + (size_t)(bn * BN + lrow) * Kdim + lcol;
  bf16_t* Asd = &As[lrow * BKg + lcol];
  bf16_t* Bsd = &Bs[lrow * BKg + lcol];

  for (int k0 = 0; k0 < Kdim; k0 += BKg) {
    __syncthreads();
#pragma unroll
    for (int j = 0; j < 4; ++j) {
      __builtin_amdgcn_global_load_lds(
          (const __attribute__((address_space(1))) void*)(Ag + (size_t)(j * 32) * Kdim + k0),
          (__attribute__((address_space(3))) void*)(Asd + j * 32 * BKg), 16, 0, 0);
      __builtin_amdgcn_global_load_lds(
          (const __attribute__((address_space(1))) void*)(Bg + (size_t)(j * 32) * Kdim + k0),
          (__attribute__((address_space(3))) void*)(Bsd + j * 32 * BKg), 16, 0, 0);
    }
    __syncthreads();
#pragma unroll
    for (int kk = 0; kk < 2; ++kk) {
      bf16x8 af[4], bfr[4];
#pragma unroll
      for (int i = 0; i < 4; ++i) {
        af[i]  = *(const bf16x8*)&As[(wm * 64 + i * 16 + (lane & 15)) * BKg + kk * 32 + (lane >> 4) * 8];
        bfr[i] = *(const bf16x8*)&Bs[(wn * 64 + i * 16 + (lane & 15)) * BKg + kk * 32 + (lane >> 4) * 8];
      }
#pragma unroll
      for (int i = 0; i < 4; ++i)
#pragma unroll
        for (int j = 0; j < 4; ++j)
          acc[i][j] = __builtin_amdgcn_mfma_f32_16x16x32_bf16(af[i], bfr[j], acc[i][j], 0, 0, 0);
    }
  }

#pragma unroll
  for (int i = 0; i < 4; ++i) {
    const int row = bm * BM + wm * 64 + i * 16 + (lane >> 4) * 4;
#pragma unroll
    for (int j = 0; j < 4; ++j) {
      const int col = bn * BN + wn * 64 + j * 16 + (lane & 15);
      const float bv = bias[col];
#pragma unroll
      for (int rg = 0; rg < 4; ++rg) {
        const float v = (acc[i][j][rg] + bv) * scale;
        if (OUT_BF16)
          ((bf16_t*)outp)[(size_t)(row + rg) * E_ + col] = (bf16_t)v;
        else
          ((float*)outp)[(size_t)(row + rg) * E_ + col] = v;
      }
    }
  }
}

// ---------------- fused dilated attention: all 5 scales + finalize, one dispatch -----
// Block = (b, h, 256-token chunk). Note w_s/256 == r_s for every scale, so each chunk
// belongs to exactly one instance per scale. Per scale: stage K/V rows (sparse gather)
// into LDS, MFMA flash over the wave's q-tiles, then merge into LDS accumulators
// (Oacc[256][68] f32, Ml/Sl) via online-LSE. Scale 0 (r=1) covers every row ->
// initializes. Epilogue normalizes and writes bf16 y. 152.5 KB LDS -> 1 block/CU.
__global__ __launch_bounds__(512, 2) void attn_fused(
    const bf16_t* __restrict__ Q, const bf16_t* __restrict__ K,
    const bf16_t* __restrict__ V, bf16_t* __restrict__ Y) {
  __shared__ alignas(16) float Oacc[256][68];   // 69632 B
  __shared__ float Ml[256];                     // 1024 B
  __shared__ float Sl[256];                     // 1024 B
  __shared__ alignas(16) bf16_t Ks[256][72];    // 36864 B
  __shared__ alignas(16) bf16_t Vt[64][264];    // 33792 B
  __shared__ alignas(16) bf16_t Pw[8][16][40];  // 10240 B   total 152576 B

  const int bid = blockIdx.x;
  const int c = bid & 15;           // chunk index within T/256
  const int h = (bid >> 4) & 15;
  const int b = bid >> 8;
  const int t0 = c * 256;

  const int t = threadIdx.x;
  const int lane = t & 63;
  const int wv = t >> 6;
  const int lc = lane & 15;         // MFMA col lane
  const int lg = lane >> 4;         // MFMA 16-lane group 0..3

  const int srow = t >> 1;          // staging: 2 threads per row
  const int sch = (t & 1) * 32;

#pragma unroll
  for (int s = 0; s < 5; ++s) {
    const int r = 1 << s;
    const int g = (h * r) >> 4;                 // head-group = dilation offset
    const int seg_base = ((c >> s) << s) * 256; // seg * w
    const int ci = c & (r - 1);                 // chunk index within segment
    const int kcnt = (ci + 1) << (8 - s);       // sparse keys needed by this chunk
    const int kstage = (kcnt + 31) & ~31;       // rounded to 32 (<=256)

    __syncthreads();  // previous scale's Ks/Vt reads + merges complete
    if (srow < kstage) {
      const int tk = seg_base + (srow << s) + g;
      const size_t off = ((size_t)b * T_ + tk) * E_ + h * 64 + sch;
      const bf16_t* Kg = K + off;
      const bf16_t* Vg = V + off;
#pragma unroll
      for (int j = 0; j < 4; ++j)
        *(bf16x8*)&Ks[srow][sch + j * 8] = *(const bf16x8*)(Kg + j * 8);
#pragma unroll
      for (int j = 0; j < 4; ++j) {
        bf16x8 va = *(const bf16x8*)(Vg + j * 8);
#pragma unroll
        for (int e = 0; e < 8; ++e) Vt[sch + j * 8 + e][srow] = va[e];
      }
    }
    __syncthreads();

    const int nt = 16 >> s;         // q-tiles this scale
    int tiles[2]; int ntw = 0;
    if (s == 0) { tiles[0] = wv; tiles[1] = 15 - wv; ntw = 2; }  // causal pairing
    else if (wv < nt) { tiles[0] = wv; ntw = 1; }

    for (int ti = 0; ti < ntw; ++ti) {
      const int j = tiles[ti];
      const int l0 = (ci << (8 - s)) + 16 * j;  // tile's base sparse position

      // Q fragments (A-frag: row=lc, k=lg*8 within each 32-k block)
      const int tq = t0 + ((16 * j + lc) << s) + g;
      const bf16_t* Qg = Q + ((size_t)b * T_ + tq) * E_ + h * 64 + lg * 8;
      bf16x8 qfrag0 = *(const bf16x8*)(Qg);
      bf16x8 qfrag1 = *(const bf16x8*)(Qg + 32);

      float m[4], Z[4];
      f32x4 Oa[4] = {};
#pragma unroll
      for (int rg = 0; rg < 4; ++rg) { m[rg] = -INFINITY; Z[rg] = 0.0f; }

      const int nkb = (l0 + 47) >> 5;
      for (int kb = 0; kb < nkb; ++kb) {
        // ---- S = Q K^T (16q x 32k) ----
        f32x4 sacc[2] = {};
#pragma unroll
        for (int kt = 0; kt < 2; ++kt) {
          bf16x8 kf0 = *(const bf16x8*)&Ks[kb * 32 + kt * 16 + lc][lg * 8];
          bf16x8 kf1 = *(const bf16x8*)&Ks[kb * 32 + kt * 16 + lc][32 + lg * 8];
          sacc[kt] = __builtin_amdgcn_mfma_f32_16x16x32_bf16(qfrag0, kf0, sacc[kt], 0, 0, 0);
          sacc[kt] = __builtin_amdgcn_mfma_f32_16x16x32_bf16(qfrag1, kf1, sacc[kt], 0, 0, 0);
        }
        // causal mask, last block only (acc: col=lc=key, row=lg*4+rg=q)
        if (kb == nkb - 1) {
#pragma unroll
          for (int kt = 0; kt < 2; ++kt) {
            const int key = kb * 32 + kt * 16 + lc;
#pragma unroll
            for (int rg = 0; rg < 4; ++rg)
              if (key > l0 + lg * 4 + rg) sacc[kt][rg] = -1e30f;
          }
        }
        // ---- online softmax per q row ----
        float crr[4];
#pragma unroll
        for (int rg = 0; rg < 4; ++rg) {
          float bm = fmaxf(sacc[0][rg], sacc[1][rg]);
          bm = fmaxf(bm, __shfl_xor(bm, 1));
          bm = fmaxf(bm, __shfl_xor(bm, 2));
          bm = fmaxf(bm, __shfl_xor(bm, 4));
          bm = fmaxf(bm, __shfl_xor(bm, 8));
          const float nm = fmaxf(m[rg], bm);
          crr[rg] = __expf(m[rg] - nm);
          m[rg] = nm;
          const float p0 = __expf(sacc[0][rg] - nm);
          const float p1 = __expf(sacc[1][rg] - nm);
          float ps = p0 + p1;
          ps += __shfl_xor(ps, 1);
          ps += __shfl_xor(ps, 2);
          ps += __shfl_xor(ps, 4);
          ps += __shfl_xor(ps, 8);
          Z[rg] = Z[rg] * crr[rg] + ps;
          Pw[wv][lg * 4 + rg][lc] = (bf16_t)p0;
          Pw[wv][lg * 4 + rg][16 + lc] = (bf16_t)p1;
        }
#pragma unroll
        for (int dt = 0; dt < 4; ++dt)
#pragma unroll
          for (int rg = 0; rg < 4; ++rg) Oa[dt][rg] *= crr[rg];
        // ---- PV ----
        bf16x8 pa = *(const bf16x8*)&Pw[wv][lc][lg * 8];
#pragma unroll
        for (int dt = 0; dt < 4; ++dt) {
          bf16x8 vf = *(const bf16x8*)&Vt[dt * 16 + lc][kb * 32 + lg * 8];
          Oa[dt] = __builtin_amdgcn_mfma_f32_16x16x32_bf16(pa, vf, Oa[dt], 0, 0, 0);
        }
      }

      // ---- merge this tile into LDS accumulators ----
#pragma unroll
      for (int rg = 0; rg < 4; ++rg) {
        const int row = ((16 * j + lg * 4 + rg) << s) + g;  // row within chunk
        const float lse = m[rg] + __logf(Z[rg]);
        const float iZ = 1.0f / Z[rg];
        if (s == 0) {
#pragma unroll
          for (int dt = 0; dt < 4; ++dt)
            Oacc[row][dt * 16 + lc] = Oa[dt][rg] * iZ;
          if (lc == 0) { Ml[row] = lse; Sl[row] = 1.0f; }
        } else {
          const float mold = Ml[row];
          const float sold = Sl[row];
          const float nM = fmaxf(mold, lse);
          const float a = __expf(mold - nM);
          const float eb = __expf(lse - nM);
          const float bw = eb * iZ;
#pragma unroll
          for (int dt = 0; dt < 4; ++dt)
            Oacc[row][dt * 16 + lc] = Oacc[row][dt * 16 + lc] * a + Oa[dt][rg] * bw;
          if (lc == 0) { Ml[row] = nM; Sl[row] = sold * a + eb; }
        }
      }
    }
  }

  __syncthreads();
  // ---- epilogue: y = Oacc / Sl -> bf16 (2 threads per row, 32 cols each) ----
  {
    const float invS = 1.0f / Sl[srow];
    bf16_t* Yo = Y + ((size_t)b * T_ + t0 + srow) * E_ + h * 64 + sch;
#pragma unroll
    for (int q = 0; q < 4; ++q) {
      f32x4 lo = *(const f32x4*)&Oacc[srow][sch + q * 8];
      f32x4 hi = *(const f32x4*)&Oacc[srow][sch + q * 8 + 4];
      bf16x8 o;
      o[0] = (bf16_t)(lo[0] * invS); o[1] = (bf16_t)(lo[1] * invS);
      o[2] = (bf16_t)(lo[2] * invS); o[3] = (bf16_t)(lo[3] * invS);
      o[4] = (bf16_t)(hi[0] * invS); o[5] = (bf16_t)(hi[1] * invS);
      o[6] = (bf16_t)(hi[2] * invS); o[7] = (bf16_t)(hi[3] * invS);
      *(bf16x8*)(Yo + q * 8) = o;
    }
  }
}

extern "C" void kernel_launch(void* const* d_in, const int* in_sizes, int n_in,
                              void* d_out, int out_size, void* d_ws, size_t ws_size,
                              hipStream_t stream) {
  (void)in_sizes; (void)n_in; (void)out_size; (void)ws_size;
  const float* x  = (const float*)d_in[0];
  const float* wq = (const float*)d_in[1];
  const float* bq = (const float*)d_in[2];
  const float* wk = (const float*)d_in[3];
  const float* bk = (const float*)d_in[4];
  const float* wv = (const float*)d_in[5];
  const float* bv = (const float*)d_in[6];
  const float* wo = (const float*)d_in[7];
  const float* bo = (const float*)d_in[8];

  char* p = (char*)d_ws;
  auto take = [&](size_t bytes) {
    char* q = p;
    p += (bytes + 255) & ~(size_t)255;
    return (void*)q;
  };
  bf16_t* wq_t = (bf16_t*)take((size_t)E_ * E_ * 2);  // wq_t/wk_t/wv_t contiguous
  bf16_t* wk_t = (bf16_t*)take((size_t)E_ * E_ * 2);
  bf16_t* wv_t = (bf16_t*)take((size_t)E_ * E_ * 2);
  bf16_t* wo_t = (bf16_t*)take((size_t)E_ * E_ * 2);
  bf16_t* xb   = (bf16_t*)take((size_t)M_ * E_ * 2);
  bf16_t* qb   = (bf16_t*)take((size_t)M_ * E_ * 2);  // qb/kbuf/vbuf contiguous
  bf16_t* kbuf = (bf16_t*)take((size_t)M_ * E_ * 2);
  bf16_t* vbuf = (bf16_t*)take((size_t)M_ * E_ * 2);
  bf16_t* yb   = (bf16_t*)take((size_t)M_ * E_ * 2);
  (void)wk_t; (void)wv_t; (void)kbuf; (void)vbuf;

  cvt_f32_bf16<<<M_ * E_ / 1024, 256, 0, stream>>>(x, xb);
  cvt_transpose_w<<<dim3(32, 32, 4), 256, 0, stream>>>(wq, wk, wv, wo, wq_t, wk_t, wv_t, wo_t);

  // Fused Q/K/V projection: grid (64, 24), output-buffer select on bn>>3.
  gemm_bt<true, true><<<dim3(M_ / BM, 3 * E_ / BN), 256, 0, stream>>>(
      xb, wq_t, bq, bk, bv, qb, E_);

  // All 5 scales + merge + finalize in one dispatch.
  attn_fused<<<B_ * 16 * 16, 512, 0, stream>>>(qb, kbuf, vbuf, yb);

  gemm_bt<false, false><<<dim3(M_ / BM, E_ / BN), 256, 0, stream>>>(
      yb, wo_t, bo, bo, bo, d_out, E_);
}

// Round 5
// 150.390 us; speedup vs baseline: 8.9520x; 1.3716x over previous
//
#include <hip/hip_runtime.h>
#include <hip/hip_bf16.h>

typedef __bf16 bf16_t;
typedef __bf16 bf16x8 __attribute__((ext_vector_type(8)));
typedef __bf16 bf16x4 __attribute__((ext_vector_type(4)));
typedef float f32x4 __attribute__((ext_vector_type(4)));
typedef int vint4 __attribute__((ext_vector_type(4)));

constexpr int B_ = 2, T_ = 4096, E_ = 1024, H_ = 16;
constexpr int M_ = B_ * T_;   // 8192 token rows

// Compact per-scale partial buffers (elem offsets). Scale s: B*H*(T>>s) rows.
__device__ constexpr size_t OB_OFF[5]  = {0, 8388608, 12582912, 14680064, 15728640};
__device__ constexpr size_t LSE_OFF[5] = {0, 131072, 196608, 229376, 245760};
constexpr size_t OB_TOTAL  = 16252928;  // elems (bf16)
constexpr size_t LSE_TOTAL = 253952;    // elems (f32)

// ---------------- f32 -> bf16 elementwise ----------------
__global__ __launch_bounds__(256) void cvt_f32_bf16(const float* __restrict__ in,
                                                    bf16_t* __restrict__ out) {
  int i = (blockIdx.x * 256 + threadIdx.x) * 4;
  const float4 v = *(const float4*)(in + i);
  bf16x4 o;
  o[0] = (bf16_t)v.x; o[1] = (bf16_t)v.y; o[2] = (bf16_t)v.z; o[3] = (bf16_t)v.w;
  *(bf16x4*)(out + i) = o;
}

// ---------------- weights: f32 [K][N] -> bf16 [N][K] (transposed) ----------------
__global__ __launch_bounds__(256) void cvt_transpose_w(
    const float* __restrict__ w0, const float* __restrict__ w1,
    const float* __restrict__ w2, const float* __restrict__ w3,
    bf16_t* __restrict__ o0, bf16_t* __restrict__ o1,
    bf16_t* __restrict__ o2, bf16_t* __restrict__ o3) {
  __shared__ float tile[32][33];
  const float* src; bf16_t* dst;
  switch (blockIdx.z) {
    case 0: src = w0; dst = o0; break;
    case 1: src = w1; dst = o1; break;
    case 2: src = w2; dst = o2; break;
    default: src = w3; dst = o3; break;
  }
  const int n0 = blockIdx.x * 32, k0 = blockIdx.y * 32;
  const int tx = threadIdx.x & 31, ty = threadIdx.x >> 5;  // 32 x 8
#pragma unroll
  for (int i = 0; i < 32; i += 8)
    tile[ty + i][tx] = src[(size_t)(k0 + ty + i) * E_ + n0 + tx];
  __syncthreads();
#pragma unroll
  for (int i = 0; i < 32; i += 8)
    dst[(size_t)(n0 + ty + i) * E_ + k0 + tx] = (bf16_t)tile[tx][ty + i];
}

// ---------------- bf16 MFMA GEMM (m97 structure: linear LDS + global_load_lds w16) ----
#define BM 128
#define BN 128
#define BKg 64

template <bool OUT_BF16, bool QKV>
__global__ __launch_bounds__(256, 2) void gemm_bt(
    const bf16_t* __restrict__ A, const bf16_t* __restrict__ BT,
    const float* __restrict__ bias0, const float* __restrict__ bias1,
    const float* __restrict__ bias2, void* __restrict__ Cout, int Kdim) {
  __shared__ bf16_t As[BM * BKg];
  __shared__ bf16_t Bs[BN * BKg];
  const int tid = threadIdx.x;
  const int lane = tid & 63;
  const int wave = tid >> 6;
  const int wm = wave >> 1, wn = wave & 1;
  const int bm = blockIdx.x;
  int bn = blockIdx.y;

  const float* bias = bias0;
  float scale = 1.0f;
  void* outp = Cout;
  if (QKV) {
    const int which = bn >> 3;
    bn &= 7;
    bias = (which == 0) ? bias0 : (which == 1) ? bias1 : bias2;
    scale = (which == 0) ? 0.125f : 1.0f;
    outp = (void*)((bf16_t*)Cout + (size_t)which * M_ * E_);
    BT += (size_t)which * E_ * E_;
  }

  f32x4 acc[4][4] = {};

  const int lrow = tid >> 3;        // 0..31
  const int lcol = (tid & 7) * 8;   // element col 0..56
  const bf16_t* Ag = A + (size_t)(bm * BM + lrow) * Kdim + lcol;
  const bf16_t* Bg = BT + (size_t)(bn * BN + lrow) * Kdim + lcol;
  bf16_t* Asd = &As[lrow * BKg + lcol];
  bf16_t* Bsd = &Bs[lrow * BKg + lcol];

  for (int k0 = 0; k0 < Kdim; k0 += BKg) {
    __syncthreads();
#pragma unroll
    for (int j = 0; j < 4; ++j) {
      __builtin_amdgcn_global_load_lds(
          (const __attribute__((address_space(1))) void*)(Ag + (size_t)(j * 32) * Kdim + k0),
          (__attribute__((address_space(3))) void*)(Asd + j * 32 * BKg), 16, 0, 0);
      __builtin_amdgcn_global_load_lds(
          (const __attribute__((address_space(1))) void*)(Bg + (size_t)(j * 32) * Kdim + k0),
          (__attribute__((address_space(3))) void*)(Bsd + j * 32 * BKg), 16, 0, 0);
    }
    __syncthreads();
#pragma unroll
    for (int kk = 0; kk < 2; ++kk) {
      bf16x8 af[4], bfr[4];
#pragma unroll
      for (int i = 0; i < 4; ++i) {
        af[i]  = *(const bf16x8*)&As[(wm * 64 + i * 16 + (lane & 15)) * BKg + kk * 32 + (lane >> 4) * 8];
        bfr[i] = *(const bf16x8*)&Bs[(wn * 64 + i * 16 + (lane & 15)) * BKg + kk * 32 + (lane >> 4) * 8];
      }
#pragma unroll
      for (int i = 0; i < 4; ++i)
#pragma unroll
        for (int j = 0; j < 4; ++j)
          acc[i][j] = __builtin_amdgcn_mfma_f32_16x16x32_bf16(af[i], bfr[j], acc[i][j], 0, 0, 0);
    }
  }

#pragma unroll
  for (int i = 0; i < 4; ++i) {
    const int row = bm * BM + wm * 64 + i * 16 + (lane >> 4) * 4;
#pragma unroll
    for (int j = 0; j < 4; ++j) {
      const int col = bn * BN + wn * 64 + j * 16 + (lane & 15);
      const float bv = bias[col];
#pragma unroll
      for (int rg = 0; rg < 4; ++rg) {
        const float v = (acc[i][j][rg] + bv) * scale;
        if (OUT_BF16)
          ((bf16_t*)outp)[(size_t)(row + rg) * E_ + col] = (bf16_t)v;
        else
          ((float*)outp)[(size_t)(row + rg) * E_ + col] = v;
      }
    }
  }
}

// ---------------- uniform causal-256 flash instance (one (scale,instance) per block) --
// 992 identical blocks, 8 waves. Swapped-QK: mfma(K,Q) -> lane holds S[key][q=lane&15];
// softmax reduce = 7 in-lane fmax + 2 shfl_xor. PV = mfma(Vt,P) -> O^T.
// Writes normalized O (bf16) + lse to compact per-scale buffers (order-free merge).
__global__ __launch_bounds__(512, 4) void attn_inst(
    const bf16_t* __restrict__ Q, const bf16_t* __restrict__ K,
    const bf16_t* __restrict__ V, bf16_t* __restrict__ Ob,
    float* __restrict__ Lse) {
  __shared__ alignas(16) bf16_t Ks[256][72];   // 36864 B
  __shared__ alignas(16) bf16_t Vt[64][264];   // 33792 B
  __shared__ alignas(16) bf16_t Pw[8][16][40]; // 10240 B  (80896 B -> 2 blocks/CU)

  const int bid = blockIdx.x;
  int s, ibase;
  if (bid < 512)      { s = 0; ibase = 0; }
  else if (bid < 768) { s = 1; ibase = 512; }
  else if (bid < 896) { s = 2; ibase = 768; }
  else if (bid < 960) { s = 3; ibase = 896; }
  else                { s = 4; ibase = 960; }
  const int inst = bid - ibase;
  const int h = inst & 15;
  const int nseg_log = 4 - s;
  const int seg = (inst >> 4) & ((1 << nseg_log) - 1);
  const int b = inst >> (4 + nseg_log);
  const int g = h >> (4 - s);      // dilation offset for this head group

  const int t = threadIdx.x;
  const int lane = t & 63;
  const int wv = t >> 6;
  const int lc = lane & 15;
  const int lg = lane >> 4;

  // ---- stage K (row-major, padded) and V (transposed) ----
  {
    const int row = t >> 1, ch = (t & 1) * 32;
    const int tk = ((seg * 256 + row) << s) + g;
    const size_t off = ((size_t)b * T_ + tk) * E_ + h * 64 + ch;
    const bf16_t* Kg = K + off;
    const bf16_t* Vg = V + off;
#pragma unroll
    for (int j = 0; j < 4; ++j)
      *(bf16x8*)&Ks[row][ch + j * 8] = *(const bf16x8*)(Kg + j * 8);
#pragma unroll
    for (int j = 0; j < 4; ++j) {
      bf16x8 va = *(const bf16x8*)(Vg + j * 8);
#pragma unroll
      for (int e = 0; e < 8; ++e) Vt[ch + j * 8 + e][row] = va[e];
    }
  }
  __syncthreads();

  const size_t rowbase = (size_t)(b * H_ + h) * (T_ >> s) + seg * 256;

#pragma unroll
  for (int sel = 0; sel < 2; ++sel) {
    const int tile = sel ? (15 - wv) : wv;   // causal load-balance pairing
    const int q = tile * 16 + lc;            // this lane's query row (swapped layout)

    const int tq = ((seg * 256 + q) << s) + g;
    const bf16_t* Qg = Q + ((size_t)b * T_ + tq) * E_ + h * 64 + lg * 8;
    bf16x8 qfrag0 = *(const bf16x8*)(Qg);
    bf16x8 qfrag1 = *(const bf16x8*)(Qg + 32);

    float m = -INFINITY, Z = 0.0f;
    f32x4 Oa[4] = {};

    const int nkb = tile / 2 + 1;
    const int diag = tile / 2;
    for (int kb = 0; kb < nkb; ++kb) {
      // ---- S^T = K Q^T (32k x 16q): lane holds S[key=kt*16+lg*4+rg][q=lc] ----
      f32x4 sacc[2] = {};
      __builtin_amdgcn_s_setprio(1);
#pragma unroll
      for (int kt = 0; kt < 2; ++kt) {
        bf16x8 kf0 = *(const bf16x8*)&Ks[kb * 32 + kt * 16 + lc][lg * 8];
        bf16x8 kf1 = *(const bf16x8*)&Ks[kb * 32 + kt * 16 + lc][32 + lg * 8];
        sacc[kt] = __builtin_amdgcn_mfma_f32_16x16x32_bf16(kf0, qfrag0, sacc[kt], 0, 0, 0);
        sacc[kt] = __builtin_amdgcn_mfma_f32_16x16x32_bf16(kf1, qfrag1, sacc[kt], 0, 0, 0);
      }
      __builtin_amdgcn_s_setprio(0);
      if (kb == diag) {
#pragma unroll
        for (int kt = 0; kt < 2; ++kt)
#pragma unroll
          for (int rg = 0; rg < 4; ++rg)
            if (kb * 32 + kt * 16 + lg * 4 + rg > q) sacc[kt][rg] = -1e30f;
      }
      // ---- online softmax: one q per lane ----
      float pm = fmaxf(fmaxf(fmaxf(sacc[0][0], sacc[0][1]), fmaxf(sacc[0][2], sacc[0][3])),
                       fmaxf(fmaxf(sacc[1][0], sacc[1][1]), fmaxf(sacc[1][2], sacc[1][3])));
      pm = fmaxf(pm, __shfl_xor(pm, 16));
      pm = fmaxf(pm, __shfl_xor(pm, 32));
      const float nm = fmaxf(m, pm);
      const float crr = __expf(m - nm);
      m = nm;
      float psum = 0.0f;
#pragma unroll
      for (int kt = 0; kt < 2; ++kt)
#pragma unroll
        for (int rg = 0; rg < 4; ++rg) {
          const float p = __expf(sacc[kt][rg] - nm);
          psum += p;
          Pw[wv][lc][kt * 16 + lg * 4 + rg] = (bf16_t)p;
        }
      psum += __shfl_xor(psum, 16);
      psum += __shfl_xor(psum, 32);
      Z = Z * crr + psum;
#pragma unroll
      for (int dt = 0; dt < 4; ++dt)
#pragma unroll
        for (int rg = 0; rg < 4; ++rg) Oa[dt][rg] *= crr;
      // ---- O^T += V^T P^T: A=Vt rows (d), B=P rows (q) ----
      bf16x8 pb = *(const bf16x8*)&Pw[wv][lc][lg * 8];
      __builtin_amdgcn_s_setprio(1);
#pragma unroll
      for (int dt = 0; dt < 4; ++dt) {
        bf16x8 vf = *(const bf16x8*)&Vt[dt * 16 + lc][kb * 32 + lg * 8];
        Oa[dt] = __builtin_amdgcn_mfma_f32_16x16x32_bf16(vf, pb, Oa[dt], 0, 0, 0);
      }
      __builtin_amdgcn_s_setprio(0);
    }

    // ---- epilogue: lane holds O[q=lc][d=dt*16+lg*4+rg] ----
    const float lse = m + __logf(Z);
    const float iZ = 1.0f / Z;
    bf16_t* orow = Ob + OB_OFF[s] + (rowbase + q) * 64 + lg * 4;
#pragma unroll
    for (int dt = 0; dt < 4; ++dt) {
      bf16x4 ov;
      ov[0] = (bf16_t)(Oa[dt][0] * iZ);
      ov[1] = (bf16_t)(Oa[dt][1] * iZ);
      ov[2] = (bf16_t)(Oa[dt][2] * iZ);
      ov[3] = (bf16_t)(Oa[dt][3] * iZ);
      *(bf16x4*)(orow + dt * 16) = ov;
    }
    if (lg == 0) Lse[LSE_OFF[s] + rowbase + q] = lse;
  }
}

// ---------------- merge scales (online LSE) + finalize to bf16 y ----------------
__global__ __launch_bounds__(256) void attn_merge(const bf16_t* __restrict__ Ob,
                                                  const float* __restrict__ Lse,
                                                  bf16_t* __restrict__ Y) {
  const int gtid = blockIdx.x * 256 + threadIdx.x;  // M*E/8 threads
  const int d8 = gtid & 7;
  const int h = (gtid >> 3) & 15;
  const int tt = (gtid >> 7) & (T_ - 1);
  const int b = gtid >> 19;

  float m = -INFINITY, S = 0.0f;
  float acc[8];
#pragma unroll
  for (int j = 0; j < 8; ++j) acc[j] = 0.0f;

#pragma unroll
  for (int s = 0; s < 5; ++s) {
    const int r = 1 << s;
    const int g = h >> (4 - s);
    if ((tt & (r - 1)) != g) continue;   // (t,h) not covered at this scale
    const size_t idx = (size_t)(b * H_ + h) * (T_ >> s) + (tt >> s);
    const float lse = Lse[LSE_OFF[s] + idx];
    const bf16x8 ov = *(const bf16x8*)(Ob + OB_OFF[s] + idx * 64 + d8 * 8);
    const float nM = fmaxf(m, lse);
    const float a = __expf(m - nM);
    const float e = __expf(lse - nM);
#pragma unroll
    for (int j = 0; j < 8; ++j) acc[j] = acc[j] * a + (float)ov[j] * e;
    S = S * a + e;
    m = nM;
  }

  const float invS = 1.0f / S;
  bf16x8 o;
#pragma unroll
  for (int j = 0; j < 8; ++j) o[j] = (bf16_t)(acc[j] * invS);
  *(bf16x8*)(Y + (size_t)gtid * 8) = o;
}

extern "C" void kernel_launch(void* const* d_in, const int* in_sizes, int n_in,
                              void* d_out, int out_size, void* d_ws, size_t ws_size,
                              hipStream_t stream) {
  (void)in_sizes; (void)n_in; (void)out_size; (void)ws_size;
  const float* x  = (const float*)d_in[0];
  const float* wq = (const float*)d_in[1];
  const float* bq = (const float*)d_in[2];
  const float* wk = (const float*)d_in[3];
  const float* bk = (const float*)d_in[4];
  const float* wv = (const float*)d_in[5];
  const float* bv = (const float*)d_in[6];
  const float* wo = (const float*)d_in[7];
  const float* bo = (const float*)d_in[8];

  char* p = (char*)d_ws;
  auto take = [&](size_t bytes) {
    char* q = p;
    p += (bytes + 255) & ~(size_t)255;
    return (void*)q;
  };
  bf16_t* wq_t = (bf16_t*)take((size_t)E_ * E_ * 2);  // wq_t/wk_t/wv_t contiguous
  bf16_t* wk_t = (bf16_t*)take((size_t)E_ * E_ * 2);
  bf16_t* wv_t = (bf16_t*)take((size_t)E_ * E_ * 2);
  bf16_t* wo_t = (bf16_t*)take((size_t)E_ * E_ * 2);
  bf16_t* xb   = (bf16_t*)take((size_t)M_ * E_ * 2);
  bf16_t* qb   = (bf16_t*)take((size_t)M_ * E_ * 2);  // qb/kbuf/vbuf contiguous
  bf16_t* kbuf = (bf16_t*)take((size_t)M_ * E_ * 2);
  bf16_t* vbuf = (bf16_t*)take((size_t)M_ * E_ * 2);
  bf16_t* yb   = (bf16_t*)take((size_t)M_ * E_ * 2);
  bf16_t* Ob   = (bf16_t*)take(OB_TOTAL * 2);
  float*  Lse  = (float*)take(LSE_TOTAL * 4);
  (void)wk_t; (void)wv_t;

  cvt_f32_bf16<<<M_ * E_ / 1024, 256, 0, stream>>>(x, xb);
  cvt_transpose_w<<<dim3(32, 32, 4), 256, 0, stream>>>(wq, wk, wv, wo, wq_t, wk_t, wv_t, wo_t);

  // Fused Q/K/V projection: grid (64, 24), output-buffer select on bn>>3.
  gemm_bt<true, true><<<dim3(M_ / BM, 3 * E_ / BN), 256, 0, stream>>>(
      xb, wq_t, bq, bk, bv, qb, E_);

  // 992 uniform causal-256 flash instances (all scales, one dispatch).
  attn_inst<<<992, 512, 0, stream>>>(qb, kbuf, vbuf, Ob, Lse);

  // Order-free LSE merge + finalize.
  attn_merge<<<M_ * E_ / 8 / 256, 256, 0, stream>>>(Ob, Lse, yb);

  gemm_bt<false, false><<<dim3(M_ / BM, E_ / BN), 256, 0, stream>>>(
      yb, wo_t, bo, bo, bo, d_out, E_);
}

// Round 6
// 147.367 us; speedup vs baseline: 9.1356x; 1.0205x over previous
//
#include <hip/hip_runtime.h>
#include <hip/hip_bf16.h>

typedef __bf16 bf16_t;
typedef __bf16 bf16x8 __attribute__((ext_vector_type(8)));
typedef __bf16 bf16x4 __attribute__((ext_vector_type(4)));
typedef float f32x4 __attribute__((ext_vector_type(4)));
typedef int vint4 __attribute__((ext_vector_type(4)));

#define AS1 __attribute__((address_space(1)))
#define AS3 __attribute__((address_space(3)))

constexpr int B_ = 2, T_ = 4096, E_ = 1024, H_ = 16;
constexpr int M_ = B_ * T_;   // 8192 token rows

// Compact per-scale partial buffers (elem offsets). Scale s: B*H*(T>>s) rows.
__device__ constexpr size_t OB_OFF[5]  = {0, 8388608, 12582912, 14680064, 15728640};
__device__ constexpr size_t LSE_OFF[5] = {0, 131072, 196608, 229376, 245760};
constexpr size_t OB_TOTAL  = 16252928;  // elems (bf16)
constexpr size_t LSE_TOTAL = 253952;    // elems (f32)

// ---------------- f32 -> bf16 elementwise ----------------
__global__ __launch_bounds__(256) void cvt_f32_bf16(const float* __restrict__ in,
                                                    bf16_t* __restrict__ out) {
  int i = (blockIdx.x * 256 + threadIdx.x) * 4;
  const float4 v = *(const float4*)(in + i);
  bf16x4 o;
  o[0] = (bf16_t)v.x; o[1] = (bf16_t)v.y; o[2] = (bf16_t)v.z; o[3] = (bf16_t)v.w;
  *(bf16x4*)(out + i) = o;
}

// ---------------- weights: f32 [K][N] -> bf16 [N][K] (transposed) ----------------
__global__ __launch_bounds__(256) void cvt_transpose_w(
    const float* __restrict__ w0, const float* __restrict__ w1,
    const float* __restrict__ w2, const float* __restrict__ w3,
    bf16_t* __restrict__ o0, bf16_t* __restrict__ o1,
    bf16_t* __restrict__ o2, bf16_t* __restrict__ o3) {
  __shared__ float tile[32][33];
  const float* src; bf16_t* dst;
  switch (blockIdx.z) {
    case 0: src = w0; dst = o0; break;
    case 1: src = w1; dst = o1; break;
    case 2: src = w2; dst = o2; break;
    default: src = w3; dst = o3; break;
  }
  const int n0 = blockIdx.x * 32, k0 = blockIdx.y * 32;
  const int tx = threadIdx.x & 31, ty = threadIdx.x >> 5;  // 32 x 8
#pragma unroll
  for (int i = 0; i < 32; i += 8)
    tile[ty + i][tx] = src[(size_t)(k0 + ty + i) * E_ + n0 + tx];
  __syncthreads();
#pragma unroll
  for (int i = 0; i < 32; i += 8)
    dst[(size_t)(n0 + ty + i) * E_ + k0 + tx] = (bf16_t)tile[tx][ty + i];
}

// ---------------- deep-pipelined bf16 MFMA GEMM --------------------------------------
// C[m][n] = (sum_k A[m][k]*BT[n][k] + bias[n]) * scale.  Tile 128x256, BK=64,
// 512 threads (8 waves 2x4, 64x64 out each). 3-buffer LDS rotation: tile t reads
// buf t%3 while tile t+2 stages into buf (t+2)%3 (held tile t-1 -> retired a full
// tile earlier: provably no write-after-read race at any phase). Two phases per
// K-tile: {12 ds_read_b128 || 3 global_load_lds; barrier; lgkmcnt(0); setprio(1);
// 16 MFMA; setprio(0); barrier}, one counted vmcnt(6) per K-tile (T4: never drain
// in-loop). T2 swizzle: LDS linear for global_load_lds, global source chunk
// pre-permuted slot^(row&7), ds_read applies the same XOR -> each 8-lane quarter
// of a b128 read covers all 32 banks.
template <bool OUT_BF16, bool QKV>
__global__ __launch_bounds__(512, 1) void gemm8p(
    const bf16_t* __restrict__ A, const bf16_t* __restrict__ BT,
    const float* __restrict__ bias0, const float* __restrict__ bias1,
    const float* __restrict__ bias2, void* __restrict__ Cout) {
  constexpr int K = E_;
  constexpr int NKT = K / 64;          // 16 K-tiles
  __shared__ bf16_t Sm[73728];         // A: 3x8192 | B: 3x16384  (147456 B)

  const int tid = threadIdx.x;
  const int lane = tid & 63;
  const int wid = tid >> 6;
  const int wm = wid >> 2, wn = wid & 3;
  const int lc = lane & 15, lg = lane >> 4;
  const int bm = blockIdx.x;
  int bn = blockIdx.y;

  const float* bias = bias0;
  float scale = 1.0f;
  void* outp = Cout;
  const bf16_t* Bt = BT;
  if (QKV) {
    const int which = bn >> 2;
    bn &= 3;
    bias = (which == 0) ? bias0 : (which == 1) ? bias1 : bias2;
    scale = (which == 0) ? 0.125f : 1.0f;
    outp = (void*)((bf16_t*)Cout + (size_t)which * M_ * E_);
    Bt += (size_t)which * E_ * E_;
  }

  // staging: thread t owns LDS bytes [t*16) of each 64-row chunk; source chunk
  // is swizzle-permuted so LDS[row][slot] = global[row][slot ^ (row&7)].
  const int srow = tid >> 3;                      // 0..63
  const int schunk = (tid & 7) ^ (srow & 7);      // (l*64 keeps row&7 == srow&7)
  const bf16_t* Ag = A + (size_t)(bm * 128 + srow) * K + schunk * 8;
  const bf16_t* Bg = Bt + (size_t)(bn * 256 + srow) * K + schunk * 8;

  // per-thread swizzled ds_read slot offsets (elems): slot = kk*4+lg, XOR row&7=lc&7
  const int sl0 = (lg ^ (lc & 7)) * 8;
  const int sl1 = ((4 + lg) ^ (lc & 7)) * 8;

  f32x4 acc[4][4] = {};

  auto stA = [&](int kt, int bu, int l) {
    __builtin_amdgcn_global_load_lds(
        (const AS1 void*)(Ag + (size_t)(l * 64) * K + kt * 64),
        (AS3 void*)(Sm + bu * 8192 + l * 4096 + tid * 8), 16, 0, 0);
  };
  auto stB = [&](int kt, int bu, int l) {
    __builtin_amdgcn_global_load_lds(
        (const AS1 void*)(Bg + (size_t)(l * 64) * K + kt * 64),
        (AS3 void*)(Sm + 24576 + bu * 16384 + l * 4096 + tid * 8), 16, 0, 0);
  };

  // prologue: tiles 0,1 fully staged; wait tile 0 only (tile 1 stays in flight)
  stA(0, 0, 0); stA(0, 0, 1);
  stB(0, 0, 0); stB(0, 0, 1); stB(0, 0, 2); stB(0, 0, 3);
  stA(1, 1, 0); stA(1, 1, 1);
  stB(1, 1, 0); stB(1, 1, 1); stB(1, 1, 2); stB(1, 1, 3);
  asm volatile("s_waitcnt vmcnt(6)" ::: "memory");
  __builtin_amdgcn_s_barrier();

  for (int kt = 0; kt < NKT; ++kt) {
    const int bc = kt % 3;
    const int bs = (kt + 2) % 3;
    const bool st = (kt + 2) < NKT;
    const int arow = bc * 8192 + (wm * 64 + lc) * 64;
    const int brow = 24576 + bc * 16384 + (wn * 64 + lc) * 64;

#pragma unroll
    for (int ph = 0; ph < 2; ++ph) {
      bf16x8 afr[2][2], bfr[4][2];
#pragma unroll
      for (int i2 = 0; i2 < 2; ++i2) {
        const int rb = arow + (ph * 32 + i2 * 16) * 64;
        afr[i2][0] = *(const bf16x8*)&Sm[rb + sl0];
        afr[i2][1] = *(const bf16x8*)&Sm[rb + sl1];
      }
#pragma unroll
      for (int j = 0; j < 4; ++j) {
        const int rb = brow + j * 16 * 64;
        bfr[j][0] = *(const bf16x8*)&Sm[rb + sl0];
        bfr[j][1] = *(const bf16x8*)&Sm[rb + sl1];
      }
      if (st) {
        if (ph == 0) { stA(kt + 2, bs, 0); stB(kt + 2, bs, 0); stB(kt + 2, bs, 1); }
        else         { stA(kt + 2, bs, 1); stB(kt + 2, bs, 2); stB(kt + 2, bs, 3); }
      }
      __builtin_amdgcn_s_barrier();
      asm volatile("s_waitcnt lgkmcnt(0)" ::: "memory");
      __builtin_amdgcn_s_setprio(1);
#pragma unroll
      for (int i2 = 0; i2 < 2; ++i2)
#pragma unroll
        for (int j = 0; j < 4; ++j) {
          acc[ph * 2 + i2][j] = __builtin_amdgcn_mfma_f32_16x16x32_bf16(
              afr[i2][0], bfr[j][0], acc[ph * 2 + i2][j], 0, 0, 0);
          acc[ph * 2 + i2][j] = __builtin_amdgcn_mfma_f32_16x16x32_bf16(
              afr[i2][1], bfr[j][1], acc[ph * 2 + i2][j], 0, 0, 0);
        }
      __builtin_amdgcn_s_setprio(0);
      if (ph == 1) {
        // tile kt+1 landed iff <= (tile kt+2's 6 loads) outstanding
        if (st) asm volatile("s_waitcnt vmcnt(6)" ::: "memory");
        else    asm volatile("s_waitcnt vmcnt(0)" ::: "memory");
      }
      __builtin_amdgcn_s_barrier();
    }
  }

#pragma unroll
  for (int i = 0; i < 4; ++i) {
    const int row = bm * 128 + wm * 64 + i * 16 + lg * 4;
#pragma unroll
    for (int j = 0; j < 4; ++j) {
      const int col = bn * 256 + wn * 64 + j * 16 + lc;
      const float bv = bias[col];
#pragma unroll
      for (int rg = 0; rg < 4; ++rg) {
        const float v = (acc[i][j][rg] + bv) * scale;
        if (OUT_BF16)
          ((bf16_t*)outp)[(size_t)(row + rg) * E_ + col] = (bf16_t)v;
        else
          ((float*)outp)[(size_t)(row + rg) * E_ + col] = v;
      }
    }
  }
}

// ---------------- uniform causal-256 flash instance (one (scale,instance) per block) --
// 992 identical blocks, 8 waves. Swapped-QK: mfma(K,Q) -> lane holds S[key][q=lane&15];
// softmax reduce = 7 in-lane fmax + 2 shfl_xor. PV = mfma(Vt,P) -> O^T.
// Writes normalized O (bf16) + lse to compact per-scale buffers (order-free merge).
__global__ __launch_bounds__(512, 4) void attn_inst(
    const bf16_t* __restrict__ Q, const bf16_t* __restrict__ K,
    const bf16_t* __restrict__ V, bf16_t* __restrict__ Ob,
    float* __restrict__ Lse) {
  __shared__ alignas(16) bf16_t Ks[256][72];   // 36864 B
  __shared__ alignas(16) bf16_t Vt[64][264];   // 33792 B
  __shared__ alignas(16) bf16_t Pw[8][16][40]; // 10240 B  (80896 B -> 2 blocks/CU)

  const int bid = blockIdx.x;
  int s, ibase;
  if (bid < 512)      { s = 0; ibase = 0; }
  else if (bid < 768) { s = 1; ibase = 512; }
  else if (bid < 896) { s = 2; ibase = 768; }
  else if (bid < 960) { s = 3; ibase = 896; }
  else                { s = 4; ibase = 960; }
  const int inst = bid - ibase;
  const int h = inst & 15;
  const int nseg_log = 4 - s;
  const int seg = (inst >> 4) & ((1 << nseg_log) - 1);
  const int b = inst >> (4 + nseg_log);
  const int g = h >> (4 - s);      // dilation offset for this head group

  const int t = threadIdx.x;
  const int lane = t & 63;
  const int wv = t >> 6;
  const int lc = lane & 15;
  const int lg = lane >> 4;

  // ---- stage K (row-major, padded) and V (transposed) ----
  {
    const int row = t >> 1, ch = (t & 1) * 32;
    const int tk = ((seg * 256 + row) << s) + g;
    const size_t off = ((size_t)b * T_ + tk) * E_ + h * 64 + ch;
    const bf16_t* Kg = K + off;
    const bf16_t* Vg = V + off;
#pragma unroll
    for (int j = 0; j < 4; ++j)
      *(bf16x8*)&Ks[row][ch + j * 8] = *(const bf16x8*)(Kg + j * 8);
#pragma unroll
    for (int j = 0; j < 4; ++j) {
      bf16x8 va = *(const bf16x8*)(Vg + j * 8);
#pragma unroll
      for (int e = 0; e < 8; ++e) Vt[ch + j * 8 + e][row] = va[e];
    }
  }
  __syncthreads();

  const size_t rowbase = (size_t)(b * H_ + h) * (T_ >> s) + seg * 256;

#pragma unroll
  for (int sel = 0; sel < 2; ++sel) {
    const int tile = sel ? (15 - wv) : wv;   // causal load-balance pairing
    const int q = tile * 16 + lc;            // this lane's query row (swapped layout)

    const int tq = ((seg * 256 + q) << s) + g;
    const bf16_t* Qg = Q + ((size_t)b * T_ + tq) * E_ + h * 64 + lg * 8;
    bf16x8 qfrag0 = *(const bf16x8*)(Qg);
    bf16x8 qfrag1 = *(const bf16x8*)(Qg + 32);

    float m = -INFINITY, Z = 0.0f;
    f32x4 Oa[4] = {};

    const int nkb = tile / 2 + 1;
    const int diag = tile / 2;
    for (int kb = 0; kb < nkb; ++kb) {
      // ---- S^T = K Q^T (32k x 16q): lane holds S[key=kt*16+lg*4+rg][q=lc] ----
      f32x4 sacc[2] = {};
      __builtin_amdgcn_s_setprio(1);
#pragma unroll
      for (int kt = 0; kt < 2; ++kt) {
        bf16x8 kf0 = *(const bf16x8*)&Ks[kb * 32 + kt * 16 + lc][lg * 8];
        bf16x8 kf1 = *(const bf16x8*)&Ks[kb * 32 + kt * 16 + lc][32 + lg * 8];
        sacc[kt] = __builtin_amdgcn_mfma_f32_16x16x32_bf16(kf0, qfrag0, sacc[kt], 0, 0, 0);
        sacc[kt] = __builtin_amdgcn_mfma_f32_16x16x32_bf16(kf1, qfrag1, sacc[kt], 0, 0, 0);
      }
      __builtin_amdgcn_s_setprio(0);
      if (kb == diag) {
#pragma unroll
        for (int kt = 0; kt < 2; ++kt)
#pragma unroll
          for (int rg = 0; rg < 4; ++rg)
            if (kb * 32 + kt * 16 + lg * 4 + rg > q) sacc[kt][rg] = -1e30f;
      }
      // ---- online softmax: one q per lane ----
      float pm = fmaxf(fmaxf(fmaxf(sacc[0][0], sacc[0][1]), fmaxf(sacc[0][2], sacc[0][3])),
                       fmaxf(fmaxf(sacc[1][0], sacc[1][1]), fmaxf(sacc[1][2], sacc[1][3])));
      pm = fmaxf(pm, __shfl_xor(pm, 16));
      pm = fmaxf(pm, __shfl_xor(pm, 32));
      const float nm = fmaxf(m, pm);
      const float crr = __expf(m - nm);
      m = nm;
      float psum = 0.0f;
#pragma unroll
      for (int kt = 0; kt < 2; ++kt)
#pragma unroll
        for (int rg = 0; rg < 4; ++rg) {
          const float p = __expf(sacc[kt][rg] - nm);
          psum += p;
          Pw[wv][lc][kt * 16 + lg * 4 + rg] = (bf16_t)p;
        }
      psum += __shfl_xor(psum, 16);
      psum += __shfl_xor(psum, 32);
      Z = Z * crr + psum;
#pragma unroll
      for (int dt = 0; dt < 4; ++dt)
#pragma unroll
        for (int rg = 0; rg < 4; ++rg) Oa[dt][rg] *= crr;
      // ---- O^T += V^T P^T: A=Vt rows (d), B=P rows (q) ----
      bf16x8 pb = *(const bf16x8*)&Pw[wv][lc][lg * 8];
      __builtin_amdgcn_s_setprio(1);
#pragma unroll
      for (int dt = 0; dt < 4; ++dt) {
        bf16x8 vf = *(const bf16x8*)&Vt[dt * 16 + lc][kb * 32 + lg * 8];
        Oa[dt] = __builtin_amdgcn_mfma_f32_16x16x32_bf16(vf, pb, Oa[dt], 0, 0, 0);
      }
      __builtin_amdgcn_s_setprio(0);
    }

    // ---- epilogue: lane holds O[q=lc][d=dt*16+lg*4+rg] ----
    const float lse = m + __logf(Z);
    const float iZ = 1.0f / Z;
    bf16_t* orow = Ob + OB_OFF[s] + (rowbase + q) * 64 + lg * 4;
#pragma unroll
    for (int dt = 0; dt < 4; ++dt) {
      bf16x4 ov;
      ov[0] = (bf16_t)(Oa[dt][0] * iZ);
      ov[1] = (bf16_t)(Oa[dt][1] * iZ);
      ov[2] = (bf16_t)(Oa[dt][2] * iZ);
      ov[3] = (bf16_t)(Oa[dt][3] * iZ);
      *(bf16x4*)(orow + dt * 16) = ov;
    }
    if (lg == 0) Lse[LSE_OFF[s] + rowbase + q] = lse;
  }
}

// ---------------- merge scales (online LSE) + finalize to bf16 y ----------------
__global__ __launch_bounds__(256) void attn_merge(const bf16_t* __restrict__ Ob,
                                                  const float* __restrict__ Lse,
                                                  bf16_t* __restrict__ Y) {
  const int gtid = blockIdx.x * 256 + threadIdx.x;  // M*E/8 threads
  const int d8 = gtid & 7;
  const int h = (gtid >> 3) & 15;
  const int tt = (gtid >> 7) & (T_ - 1);
  const int b = gtid >> 19;

  float m = -INFINITY, S = 0.0f;
  float acc[8];
#pragma unroll
  for (int j = 0; j < 8; ++j) acc[j] = 0.0f;

#pragma unroll
  for (int s = 0; s < 5; ++s) {
    const int r = 1 << s;
    const int g = h >> (4 - s);
    if ((tt & (r - 1)) != g) continue;   // (t,h) not covered at this scale
    const size_t idx = (size_t)(b * H_ + h) * (T_ >> s) + (tt >> s);
    const float lse = Lse[LSE_OFF[s] + idx];
    const bf16x8 ov = *(const bf16x8*)(Ob + OB_OFF[s] + idx * 64 + d8 * 8);
    const float nM = fmaxf(m, lse);
    const float a = __expf(m - nM);
    const float e = __expf(lse - nM);
#pragma unroll
    for (int j = 0; j < 8; ++j) acc[j] = acc[j] * a + (float)ov[j] * e;
    S = S * a + e;
    m = nM;
  }

  const float invS = 1.0f / S;
  bf16x8 o;
#pragma unroll
  for (int j = 0; j < 8; ++j) o[j] = (bf16_t)(acc[j] * invS);
  *(bf16x8*)(Y + (size_t)gtid * 8) = o;
}

extern "C" void kernel_launch(void* const* d_in, const int* in_sizes, int n_in,
                              void* d_out, int out_size, void* d_ws, size_t ws_size,
                              hipStream_t stream) {
  (void)in_sizes; (void)n_in; (void)out_size; (void)ws_size;
  const float* x  = (const float*)d_in[0];
  const float* wq = (const float*)d_in[1];
  const float* bq = (const float*)d_in[2];
  const float* wk = (const float*)d_in[3];
  const float* bk = (const float*)d_in[4];
  const float* wv = (const float*)d_in[5];
  const float* bv = (const float*)d_in[6];
  const float* wo = (const float*)d_in[7];
  const float* bo = (const float*)d_in[8];

  char* p = (char*)d_ws;
  auto take = [&](size_t bytes) {
    char* q = p;
    p += (bytes + 255) & ~(size_t)255;
    return (void*)q;
  };
  bf16_t* wq_t = (bf16_t*)take((size_t)E_ * E_ * 2);  // wq_t/wk_t/wv_t contiguous
  bf16_t* wk_t = (bf16_t*)take((size_t)E_ * E_ * 2);
  bf16_t* wv_t = (bf16_t*)take((size_t)E_ * E_ * 2);
  bf16_t* wo_t = (bf16_t*)take((size_t)E_ * E_ * 2);
  bf16_t* xb   = (bf16_t*)take((size_t)M_ * E_ * 2);
  bf16_t* qb   = (bf16_t*)take((size_t)M_ * E_ * 2);  // qb/kbuf/vbuf contiguous
  bf16_t* kbuf = (bf16_t*)take((size_t)M_ * E_ * 2);
  bf16_t* vbuf = (bf16_t*)take((size_t)M_ * E_ * 2);
  bf16_t* yb   = (bf16_t*)take((size_t)M_ * E_ * 2);
  bf16_t* Ob   = (bf16_t*)take(OB_TOTAL * 2);
  float*  Lse  = (float*)take(LSE_TOTAL * 4);
  (void)wk_t; (void)wv_t;

  cvt_f32_bf16<<<M_ * E_ / 1024, 256, 0, stream>>>(x, xb);
  cvt_transpose_w<<<dim3(32, 32, 4), 256, 0, stream>>>(wq, wk, wv, wo, wq_t, wk_t, wv_t, wo_t);

  // Fused Q/K/V projection: grid (64, 12), output-buffer select on bn>>2.
  gemm8p<true, true><<<dim3(M_ / 128, 12), 512, 0, stream>>>(
      xb, wq_t, bq, bk, bv, qb);

  // 992 uniform causal-256 flash instances (all scales, one dispatch).
  attn_inst<<<992, 512, 0, stream>>>(qb, kbuf, vbuf, Ob, Lse);

  // Order-free LSE merge + finalize.
  attn_merge<<<M_ * E_ / 8 / 256, 256, 0, stream>>>(Ob, Lse, yb);

  gemm8p<false, false><<<dim3(M_ / 128, 4), 512, 0, stream>>>(
      yb, wo_t, bo, bo, bo, d_out);
}

// Round 7
// 137.989 us; speedup vs baseline: 9.7564x; 1.0680x over previous
//
#include <hip/hip_runtime.h>
#include <hip/hip_bf16.h>

typedef __bf16 bf16_t;
typedef __bf16 bf16x8 __attribute__((ext_vector_type(8)));
typedef __bf16 bf16x4 __attribute__((ext_vector_type(4)));
typedef float f32x4 __attribute__((ext_vector_type(4)));
typedef int vint4 __attribute__((ext_vector_type(4)));

#define AS1 __attribute__((address_space(1)))
#define AS3 __attribute__((address_space(3)))

constexpr int B_ = 2, T_ = 4096, E_ = 1024, H_ = 16;
constexpr int M_ = B_ * T_;   // 8192 token rows

// Compact per-scale partial buffers (elem offsets). Scale s: B*H*(T>>s) rows.
__device__ constexpr size_t OB_OFF[5]  = {0, 8388608, 12582912, 14680064, 15728640};
__device__ constexpr size_t LSE_OFF[5] = {0, 131072, 196608, 229376, 245760};
constexpr size_t OB_TOTAL  = 16252928;  // elems (bf16)
constexpr size_t LSE_TOTAL = 253952;    // elems (f32)

// ---------------- f32 -> bf16 elementwise ----------------
__global__ __launch_bounds__(256) void cvt_f32_bf16(const float* __restrict__ in,
                                                    bf16_t* __restrict__ out) {
  int i = (blockIdx.x * 256 + threadIdx.x) * 4;
  const float4 v = *(const float4*)(in + i);
  bf16x4 o;
  o[0] = (bf16_t)v.x; o[1] = (bf16_t)v.y; o[2] = (bf16_t)v.z; o[3] = (bf16_t)v.w;
  *(bf16x4*)(out + i) = o;
}

// ---------------- weights: f32 [K][N] -> bf16 [N][K] (transposed) ----------------
__global__ __launch_bounds__(256) void cvt_transpose_w(
    const float* __restrict__ w0, const float* __restrict__ w1,
    const float* __restrict__ w2, const float* __restrict__ w3,
    bf16_t* __restrict__ o0, bf16_t* __restrict__ o1,
    bf16_t* __restrict__ o2, bf16_t* __restrict__ o3) {
  __shared__ float tile[32][33];
  const float* src; bf16_t* dst;
  switch (blockIdx.z) {
    case 0: src = w0; dst = o0; break;
    case 1: src = w1; dst = o1; break;
    case 2: src = w2; dst = o2; break;
    default: src = w3; dst = o3; break;
  }
  const int n0 = blockIdx.x * 32, k0 = blockIdx.y * 32;
  const int tx = threadIdx.x & 31, ty = threadIdx.x >> 5;  // 32 x 8
#pragma unroll
  for (int i = 0; i < 32; i += 8)
    tile[ty + i][tx] = src[(size_t)(k0 + ty + i) * E_ + n0 + tx];
  __syncthreads();
#pragma unroll
  for (int i = 0; i < 32; i += 8)
    dst[(size_t)(n0 + ty + i) * E_ + k0 + tx] = (bf16_t)tile[tx][ty + i];
}

// ---------------- deep-pipelined bf16 MFMA GEMM, v2 ----------------------------------
// C[m][n] = (sum_k A[m][k]*BT[n][k] + bias[n]) * scale.  Tile 256x128, BK=64,
// 512 threads = 8 waves (4M x 2N), wave tile 64x64, acc[4][4].  Per K-tile:
// {issue 6 global_load_lds for tile t+2 (3-buffer rotation); s_waitcnt vmcnt(12)
// (tile t landed, t+1/t+2 stay in flight); s_barrier; 16 ds_read_b128 + 32 MFMA
// (NO explicit lgkmcnt -- compiler emits partial waits so reads/MFMA interleave);
// s_barrier}.  T2 swizzle: LDS linear (global_load_lds dest), global source chunk
// pre-permuted (tid&7)^(row&7), ds_read slot XOR'd the same way -> per-16-lane
// read phase hits 8 distinct 16B slots = conflict-free (verified R6: conflicts=0).
// Race-freedom: stage(t+2) writes buf (t+2)%3, last read at tile t-1, whose reads
// completed before the end-of-(t-1) barrier that precedes this issue point.
template <bool OUT_BF16, bool QKV>
__global__ __launch_bounds__(512, 1) void gemm_dp(
    const bf16_t* __restrict__ A, const bf16_t* __restrict__ BT,
    const float* __restrict__ bias0, const float* __restrict__ bias1,
    const float* __restrict__ bias2, void* __restrict__ Cout) {
  constexpr int K = E_;
  constexpr int NT = K / 64;           // 16 K-tiles
  __shared__ bf16_t Sm[73728];         // A: 3x16384 | B: 3x8192  (147456 B)

  const int tid = threadIdx.x;
  const int lane = tid & 63;
  const int wid = tid >> 6;
  const int wm = wid >> 1, wn = wid & 1;   // 4M x 2N waves
  const int lc = lane & 15, lg = lane >> 4;
  const int bm = blockIdx.x;
  int bn = blockIdx.y;

  const float* bias = bias0;
  float scale = 1.0f;
  void* outp = Cout;
  const bf16_t* Bt = BT;
  if (QKV) {
    const int which = bn >> 3;
    bn &= 7;
    bias = (which == 0) ? bias0 : (which == 1) ? bias1 : bias2;
    scale = (which == 0) ? 0.125f : 1.0f;
    outp = (void*)((bf16_t*)Cout + (size_t)which * M_ * E_);
    Bt += (size_t)which * E_ * E_;
  }

  const int srow = tid >> 3;                      // 0..63
  const int schunk = (tid & 7) ^ (srow & 7);      // source-side swizzle
  const bf16_t* Ag = A + (size_t)(bm * 256 + srow) * K + schunk * 8;
  const bf16_t* Bg = Bt + (size_t)(bn * 128 + srow) * K + schunk * 8;

  auto stA = [&](int kt, int bu) {
#pragma unroll
    for (int l = 0; l < 4; ++l)
      __builtin_amdgcn_global_load_lds(
          (const AS1 void*)(Ag + (size_t)(l * 64) * K + kt * 64),
          (AS3 void*)(Sm + bu * 16384 + l * 4096 + tid * 8), 16, 0, 0);
  };
  auto stB = [&](int kt, int bu) {
#pragma unroll
    for (int l = 0; l < 2; ++l)
      __builtin_amdgcn_global_load_lds(
          (const AS1 void*)(Bg + (size_t)(l * 64) * K + kt * 64),
          (AS3 void*)(Sm + 49152 + bu * 8192 + l * 4096 + tid * 8), 16, 0, 0);
  };

  // swizzled ds_read slot offsets (elems): slot = kk*4+lg, XOR row&7 (= lc&7)
  const int sl0 = ((lg) ^ (lc & 7)) * 8;
  const int sl1 = ((4 + lg) ^ (lc & 7)) * 8;

  f32x4 acc[4][4] = {};

  stA(0, 0); stB(0, 0);
  stA(1, 1); stB(1, 1);

  for (int kt = 0; kt < NT; ++kt) {
    const int bc = kt % 3;
    if (kt + 2 < NT) {
      const int bs = (kt + 2) % 3;
      stA(kt + 2, bs); stB(kt + 2, bs);
      asm volatile("s_waitcnt vmcnt(12)" ::: "memory");
    } else if (kt + 1 < NT) {
      asm volatile("s_waitcnt vmcnt(6)" ::: "memory");
    } else {
      asm volatile("s_waitcnt vmcnt(0)" ::: "memory");
    }
    __builtin_amdgcn_s_barrier();
    asm volatile("" ::: "memory");   // fence: no ds_read hoisted above barrier

    const int ab = bc * 16384 + (wm * 64 + lc) * 64;
    const int bb = 49152 + bc * 8192 + (wn * 64 + lc) * 64;
    bf16x8 afr[4][2], bfr[4][2];
#pragma unroll
    for (int i = 0; i < 4; ++i) {
      afr[i][0] = *(const bf16x8*)&Sm[ab + i * 1024 + sl0];
      afr[i][1] = *(const bf16x8*)&Sm[ab + i * 1024 + sl1];
    }
#pragma unroll
    for (int j = 0; j < 4; ++j) {
      bfr[j][0] = *(const bf16x8*)&Sm[bb + j * 1024 + sl0];
      bfr[j][1] = *(const bf16x8*)&Sm[bb + j * 1024 + sl1];
    }
#pragma unroll
    for (int i = 0; i < 4; ++i)
#pragma unroll
      for (int j = 0; j < 4; ++j) {
        acc[i][j] = __builtin_amdgcn_mfma_f32_16x16x32_bf16(afr[i][0], bfr[j][0], acc[i][j], 0, 0, 0);
        acc[i][j] = __builtin_amdgcn_mfma_f32_16x16x32_bf16(afr[i][1], bfr[j][1], acc[i][j], 0, 0, 0);
      }
    asm volatile("" ::: "memory");   // fence: no ds_read sunk below barrier
    __builtin_amdgcn_s_barrier();
  }

#pragma unroll
  for (int i = 0; i < 4; ++i) {
    const int row = bm * 256 + wm * 64 + i * 16 + lg * 4;
#pragma unroll
    for (int j = 0; j < 4; ++j) {
      const int col = bn * 128 + wn * 64 + j * 16 + lc;
      const float bv = bias[col];
#pragma unroll
      for (int rg = 0; rg < 4; ++rg) {
        const float v = (acc[i][j][rg] + bv) * scale;
        if (OUT_BF16)
          ((bf16_t*)outp)[(size_t)(row + rg) * E_ + col] = (bf16_t)v;
        else
          ((float*)outp)[(size_t)(row + rg) * E_ + col] = v;
      }
    }
  }
}

// ---------------- uniform causal-256 flash instance (one (scale,instance) per block) --
// 992 identical blocks, 8 waves. Swapped-QK: mfma(K,Q) -> lane holds S[key][q=lane&15];
// softmax reduce = 7 in-lane fmax + 2 shfl_xor. PV = mfma(Vt,P) -> O^T.
// Writes normalized O (bf16) + lse to compact per-scale buffers (order-free merge).
__global__ __launch_bounds__(512, 4) void attn_inst(
    const bf16_t* __restrict__ Q, const bf16_t* __restrict__ K,
    const bf16_t* __restrict__ V, bf16_t* __restrict__ Ob,
    float* __restrict__ Lse) {
  __shared__ alignas(16) bf16_t Ks[256][72];   // 36864 B
  __shared__ alignas(16) bf16_t Vt[64][264];   // 33792 B
  __shared__ alignas(16) bf16_t Pw[8][16][40]; // 10240 B  (80896 B -> 2 blocks/CU)

  const int bid = blockIdx.x;
  int s, ibase;
  if (bid < 512)      { s = 0; ibase = 0; }
  else if (bid < 768) { s = 1; ibase = 512; }
  else if (bid < 896) { s = 2; ibase = 768; }
  else if (bid < 960) { s = 3; ibase = 896; }
  else                { s = 4; ibase = 960; }
  const int inst = bid - ibase;
  const int h = inst & 15;
  const int nseg_log = 4 - s;
  const int seg = (inst >> 4) & ((1 << nseg_log) - 1);
  const int b = inst >> (4 + nseg_log);
  const int g = h >> (4 - s);      // dilation offset for this head group

  const int t = threadIdx.x;
  const int lane = t & 63;
  const int wv = t >> 6;
  const int lc = lane & 15;
  const int lg = lane >> 4;

  // ---- stage K (row-major, padded) and V (transposed) ----
  {
    const int row = t >> 1, ch = (t & 1) * 32;
    const int tk = ((seg * 256 + row) << s) + g;
    const size_t off = ((size_t)b * T_ + tk) * E_ + h * 64 + ch;
    const bf16_t* Kg = K + off;
    const bf16_t* Vg = V + off;
#pragma unroll
    for (int j = 0; j < 4; ++j)
      *(bf16x8*)&Ks[row][ch + j * 8] = *(const bf16x8*)(Kg + j * 8);
#pragma unroll
    for (int j = 0; j < 4; ++j) {
      bf16x8 va = *(const bf16x8*)(Vg + j * 8);
#pragma unroll
      for (int e = 0; e < 8; ++e) Vt[ch + j * 8 + e][row] = va[e];
    }
  }
  __syncthreads();

  const size_t rowbase = (size_t)(b * H_ + h) * (T_ >> s) + seg * 256;

#pragma unroll
  for (int sel = 0; sel < 2; ++sel) {
    const int tile = sel ? (15 - wv) : wv;   // causal load-balance pairing
    const int q = tile * 16 + lc;            // this lane's query row (swapped layout)

    const int tq = ((seg * 256 + q) << s) + g;
    const bf16_t* Qg = Q + ((size_t)b * T_ + tq) * E_ + h * 64 + lg * 8;
    bf16x8 qfrag0 = *(const bf16x8*)(Qg);
    bf16x8 qfrag1 = *(const bf16x8*)(Qg + 32);

    float m = -INFINITY, Z = 0.0f;
    f32x4 Oa[4] = {};

    const int nkb = tile / 2 + 1;
    const int diag = tile / 2;
    for (int kb = 0; kb < nkb; ++kb) {
      // ---- S^T = K Q^T (32k x 16q): lane holds S[key=kt*16+lg*4+rg][q=lc] ----
      f32x4 sacc[2] = {};
      __builtin_amdgcn_s_setprio(1);
#pragma unroll
      for (int kt = 0; kt < 2; ++kt) {
        bf16x8 kf0 = *(const bf16x8*)&Ks[kb * 32 + kt * 16 + lc][lg * 8];
        bf16x8 kf1 = *(const bf16x8*)&Ks[kb * 32 + kt * 16 + lc][32 + lg * 8];
        sacc[kt] = __builtin_amdgcn_mfma_f32_16x16x32_bf16(kf0, qfrag0, sacc[kt], 0, 0, 0);
        sacc[kt] = __builtin_amdgcn_mfma_f32_16x16x32_bf16(kf1, qfrag1, sacc[kt], 0, 0, 0);
      }
      __builtin_amdgcn_s_setprio(0);
      if (kb == diag) {
#pragma unroll
        for (int kt = 0; kt < 2; ++kt)
#pragma unroll
          for (int rg = 0; rg < 4; ++rg)
            if (kb * 32 + kt * 16 + lg * 4 + rg > q) sacc[kt][rg] = -1e30f;
      }
      // ---- online softmax: one q per lane ----
      float pm = fmaxf(fmaxf(fmaxf(sacc[0][0], sacc[0][1]), fmaxf(sacc[0][2], sacc[0][3])),
                       fmaxf(fmaxf(sacc[1][0], sacc[1][1]), fmaxf(sacc[1][2], sacc[1][3])));
      pm = fmaxf(pm, __shfl_xor(pm, 16));
      pm = fmaxf(pm, __shfl_xor(pm, 32));
      const float nm = fmaxf(m, pm);
      const float crr = __expf(m - nm);
      m = nm;
      float psum = 0.0f;
#pragma unroll
      for (int kt = 0; kt < 2; ++kt)
#pragma unroll
        for (int rg = 0; rg < 4; ++rg) {
          const float p = __expf(sacc[kt][rg] - nm);
          psum += p;
          Pw[wv][lc][kt * 16 + lg * 4 + rg] = (bf16_t)p;
        }
      psum += __shfl_xor(psum, 16);
      psum += __shfl_xor(psum, 32);
      Z = Z * crr + psum;
#pragma unroll
      for (int dt = 0; dt < 4; ++dt)
#pragma unroll
        for (int rg = 0; rg < 4; ++rg) Oa[dt][rg] *= crr;
      // ---- O^T += V^T P^T: A=Vt rows (d), B=P rows (q) ----
      bf16x8 pb = *(const bf16x8*)&Pw[wv][lc][lg * 8];
      __builtin_amdgcn_s_setprio(1);
#pragma unroll
      for (int dt = 0; dt < 4; ++dt) {
        bf16x8 vf = *(const bf16x8*)&Vt[dt * 16 + lc][kb * 32 + lg * 8];
        Oa[dt] = __builtin_amdgcn_mfma_f32_16x16x32_bf16(vf, pb, Oa[dt], 0, 0, 0);
      }
      __builtin_amdgcn_s_setprio(0);
    }

    // ---- epilogue: lane holds O[q=lc][d=dt*16+lg*4+rg] ----
    const float lse = m + __logf(Z);
    const float iZ = 1.0f / Z;
    bf16_t* orow = Ob + OB_OFF[s] + (rowbase + q) * 64 + lg * 4;
#pragma unroll
    for (int dt = 0; dt < 4; ++dt) {
      bf16x4 ov;
      ov[0] = (bf16_t)(Oa[dt][0] * iZ);
      ov[1] = (bf16_t)(Oa[dt][1] * iZ);
      ov[2] = (bf16_t)(Oa[dt][2] * iZ);
      ov[3] = (bf16_t)(Oa[dt][3] * iZ);
      *(bf16x4*)(orow + dt * 16) = ov;
    }
    if (lg == 0) Lse[LSE_OFF[s] + rowbase + q] = lse;
  }
}

// ---------------- merge scales (online LSE) + finalize to bf16 y ----------------
__global__ __launch_bounds__(256) void attn_merge(const bf16_t* __restrict__ Ob,
                                                  const float* __restrict__ Lse,
                                                  bf16_t* __restrict__ Y) {
  const int gtid = blockIdx.x * 256 + threadIdx.x;  // M*E/8 threads
  const int d8 = gtid & 7;
  const int h = (gtid >> 3) & 15;
  const int tt = (gtid >> 7) & (T_ - 1);
  const int b = gtid >> 19;

  float m = -INFINITY, S = 0.0f;
  float acc[8];
#pragma unroll
  for (int j = 0; j < 8; ++j) acc[j] = 0.0f;

#pragma unroll
  for (int s = 0; s < 5; ++s) {
    const int r = 1 << s;
    const int g = h >> (4 - s);
    if ((tt & (r - 1)) != g) continue;   // (t,h) not covered at this scale
    const size_t idx = (size_t)(b * H_ + h) * (T_ >> s) + (tt >> s);
    const float lse = Lse[LSE_OFF[s] + idx];
    const bf16x8 ov = *(const bf16x8*)(Ob + OB_OFF[s] + idx * 64 + d8 * 8);
    const float nM = fmaxf(m, lse);
    const float a = __expf(m - nM);
    const float e = __expf(lse - nM);
#pragma unroll
    for (int j = 0; j < 8; ++j) acc[j] = acc[j] * a + (float)ov[j] * e;
    S = S * a + e;
    m = nM;
  }

  const float invS = 1.0f / S;
  bf16x8 o;
#pragma unroll
  for (int j = 0; j < 8; ++j) o[j] = (bf16_t)(acc[j] * invS);
  *(bf16x8*)(Y + (size_t)gtid * 8) = o;
}

extern "C" void kernel_launch(void* const* d_in, const int* in_sizes, int n_in,
                              void* d_out, int out_size, void* d_ws, size_t ws_size,
                              hipStream_t stream) {
  (void)in_sizes; (void)n_in; (void)out_size; (void)ws_size;
  const float* x  = (const float*)d_in[0];
  const float* wq = (const float*)d_in[1];
  const float* bq = (const float*)d_in[2];
  const float* wk = (const float*)d_in[3];
  const float* bk = (const float*)d_in[4];
  const float* wv = (const float*)d_in[5];
  const float* bv = (const float*)d_in[6];
  const float* wo = (const float*)d_in[7];
  const float* bo = (const float*)d_in[8];

  char* p = (char*)d_ws;
  auto take = [&](size_t bytes) {
    char* q = p;
    p += (bytes + 255) & ~(size_t)255;
    return (void*)q;
  };
  bf16_t* wq_t = (bf16_t*)take((size_t)E_ * E_ * 2);  // wq_t/wk_t/wv_t contiguous
  bf16_t* wk_t = (bf16_t*)take((size_t)E_ * E_ * 2);
  bf16_t* wv_t = (bf16_t*)take((size_t)E_ * E_ * 2);
  bf16_t* wo_t = (bf16_t*)take((size_t)E_ * E_ * 2);
  bf16_t* xb   = (bf16_t*)take((size_t)M_ * E_ * 2);
  bf16_t* qb   = (bf16_t*)take((size_t)M_ * E_ * 2);  // qb/kbuf/vbuf contiguous
  bf16_t* kbuf = (bf16_t*)take((size_t)M_ * E_ * 2);
  bf16_t* vbuf = (bf16_t*)take((size_t)M_ * E_ * 2);
  bf16_t* yb   = (bf16_t*)take((size_t)M_ * E_ * 2);
  bf16_t* Ob   = (bf16_t*)take(OB_TOTAL * 2);
  float*  Lse  = (float*)take(LSE_TOTAL * 4);
  (void)wk_t; (void)wv_t;

  cvt_f32_bf16<<<M_ * E_ / 1024, 256, 0, stream>>>(x, xb);
  cvt_transpose_w<<<dim3(32, 32, 4), 256, 0, stream>>>(wq, wk, wv, wo, wq_t, wk_t, wv_t, wo_t);

  // Fused Q/K/V projection: grid (32, 24) = 768 blocks = 3 exact CU-waves.
  gemm_dp<true, true><<<dim3(M_ / 256, 24), 512, 0, stream>>>(
      xb, wq_t, bq, bk, bv, qb);

  // 992 uniform causal-256 flash instances (all scales, one dispatch).
  attn_inst<<<992, 512, 0, stream>>>(qb, kbuf, vbuf, Ob, Lse);

  // Order-free LSE merge + finalize.
  attn_merge<<<M_ * E_ / 8 / 256, 256, 0, stream>>>(Ob, Lse, yb);

  // Output projection: grid (32, 8) = 256 blocks = 1 exact CU-wave.
  gemm_dp<false, false><<<dim3(M_ / 256, 8), 512, 0, stream>>>(
      yb, wo_t, bo, bo, bo, d_out);
}